// Round 1
// baseline (3012.819 us; speedup 1.0000x reference)
//
#include <hip/hip_runtime.h>
#include <hip/hip_bf16.h>
#include <cstdint>

#define B_SZ  2048
#define D_INN 1024
#define H_SZ  2048
#define D_OUTN 1024
#define TMAX  12

// ---------------------------------------------------------------------------
// GEMM (NT): C[m,n] = sum_k A[m,k] * B[n,k]  (+ Cadd[m,n]) (+ radd[n])
// A row-major [M,K] lda, B row-major [N,K] ldb (weights), C row-major ldc.
// Tile: BM=128 x BN=64, BK=16, 256 threads, 8x4 microtile, reg prefetch.
// ---------------------------------------------------------------------------
constexpr int BM = 128, BN = 64, BK = 16;

__global__ __launch_bounds__(256) void gemm_nt(
    const float* __restrict__ A, int lda,
    const float* __restrict__ B, int ldb,
    const float* __restrict__ Cadd,   // may be null; indexed with ldc
    const float* __restrict__ radd,   // may be null; [N]
    float* __restrict__ C, int ldc,
    int K)
{
    __shared__ float As[BK][BM + 4];   // row = 132 floats (16B aligned, 2-way banks)
    __shared__ float Bs[BK][BN + 4];   // row = 68 floats
    const int tid  = threadIdx.x;
    const int m0   = blockIdx.y * BM;
    const int n0   = blockIdx.x * BN;
    const int tm   = tid >> 4;          // 0..15 -> 8 rows each
    const int tn   = tid & 15;          // 0..15 -> 4 cols each
    const int lrow = tid >> 2;          // 0..63
    const int lkc  = (tid & 3) << 2;    // 0,4,8,12

    float acc[8][4];
#pragma unroll
    for (int i = 0; i < 8; ++i)
#pragma unroll
        for (int j = 0; j < 4; ++j) acc[i][j] = 0.f;

    const float* Aptr = A + (size_t)(m0 + lrow) * lda + lkc;
    const float* A2ptr = Aptr + (size_t)64 * lda;
    const float* Bptr = B + (size_t)(n0 + lrow) * ldb + lkc;

    float4 a0 = *(const float4*)(Aptr);
    float4 a1 = *(const float4*)(A2ptr);
    float4 b0 = *(const float4*)(Bptr);

    for (int k0 = 0; k0 < K; k0 += BK) {
        __syncthreads();
        As[lkc + 0][lrow]      = a0.x; As[lkc + 1][lrow]      = a0.y;
        As[lkc + 2][lrow]      = a0.z; As[lkc + 3][lrow]      = a0.w;
        As[lkc + 0][lrow + 64] = a1.x; As[lkc + 1][lrow + 64] = a1.y;
        As[lkc + 2][lrow + 64] = a1.z; As[lkc + 3][lrow + 64] = a1.w;
        Bs[lkc + 0][lrow]      = b0.x; Bs[lkc + 1][lrow]      = b0.y;
        Bs[lkc + 2][lrow]      = b0.z; Bs[lkc + 3][lrow]      = b0.w;
        __syncthreads();
        if (k0 + BK < K) {           // prefetch next tile into regs (hidden under FMAs)
            a0 = *(const float4*)(Aptr + k0 + BK);
            a1 = *(const float4*)(A2ptr + k0 + BK);
            b0 = *(const float4*)(Bptr + k0 + BK);
        }
#pragma unroll
        for (int k = 0; k < BK; ++k) {
            float4 av0 = *(const float4*)&As[k][tm * 8];
            float4 av1 = *(const float4*)&As[k][tm * 8 + 4];
            float4 bv  = *(const float4*)&Bs[k][tn * 4];
            float am[8] = {av0.x, av0.y, av0.z, av0.w, av1.x, av1.y, av1.z, av1.w};
            float bn[4] = {bv.x, bv.y, bv.z, bv.w};
#pragma unroll
            for (int i = 0; i < 8; ++i)
#pragma unroll
                for (int j = 0; j < 4; ++j)
                    acc[i][j] = fmaf(am[i], bn[j], acc[i][j]);
        }
    }

#pragma unroll
    for (int i = 0; i < 8; ++i) {
        const int row = m0 + tm * 8 + i;
        const int col = n0 + tn * 4;
        float4 r = make_float4(acc[i][0], acc[i][1], acc[i][2], acc[i][3]);
        if (Cadd) {
            float4 c = *(const float4*)(Cadd + (size_t)row * ldc + col);
            r.x += c.x; r.y += c.y; r.z += c.z; r.w += c.w;
        }
        if (radd) {
            float4 rb = *(const float4*)(radd + col);
            r.x += rb.x; r.y += rb.y; r.z += rb.z; r.w += rb.w;
        }
        *(float4*)(C + (size_t)row * ldc + col) = r;
    }
}

// rsum[j] = sum_{k<K} W[j,k]   (the (x+1)-vs-x correction for t==0)
__global__ __launch_bounds__(256) void rowsum_kernel(
    const float* __restrict__ W, int ld, int K, float* __restrict__ out)
{
    const int j = blockIdx.x;
    const int tid = threadIdx.x;
    float s = 0.f;
    for (int k = tid; k < K; k += 256) s += W[(size_t)j * ld + k];
#pragma unroll
    for (int off = 32; off; off >>= 1) s += __shfl_down(s, off);
    __shared__ float red[4];
    if ((tid & 63) == 0) red[tid >> 6] = s;
    __syncthreads();
    if (tid == 0) out[j] = red[0] + red[1] + red[2] + red[3];
}

// Per-step halting logic + weighted accumulation of hidden (online ACT).
// One block (256 thr) per batch row.
__global__ __launch_bounds__(256) void halt_accum(
    const float* __restrict__ s_new,   // [B,H]
    const float* __restrict__ w_halt,  // [H]
    const float* __restrict__ b_halt,  // [1]
    float* __restrict__ hidden,        // [B,H] accumulator (in d_out)
    float* __restrict__ ponder,        // [B]   (in d_out)
    float* __restrict__ cumB,          // [B] state
    float* __restrict__ Rv,            // [B] state
    float* __restrict__ nstep,         // [B] state
    int*   __restrict__ halted,        // [B] state
    int t)
{
    const int b = blockIdx.x;
    const int tid = threadIdx.x;
    const float* row = s_new + (size_t)b * H_SZ;

    float4 s0 = *(const float4*)(row + tid * 8);
    float4 s1 = *(const float4*)(row + tid * 8 + 4);
    float4 w0 = *(const float4*)(w_halt + tid * 8);
    float4 w1 = *(const float4*)(w_halt + tid * 8 + 4);
    float part = s0.x * w0.x + s0.y * w0.y + s0.z * w0.z + s0.w * w0.w
               + s1.x * w1.x + s1.y * w1.y + s1.z * w1.z + s1.w * w1.w;
#pragma unroll
    for (int off = 32; off; off >>= 1) part += __shfl_down(part, off);

    __shared__ float red[4];
    __shared__ float w_sh;
    if ((tid & 63) == 0) red[tid >> 6] = part;
    __syncthreads();
    if (tid == 0) {
        const float dot = red[0] + red[1] + red[2] + red[3] + b_halt[0];
        const float p = 1.f / (1.f + expf(-dot));
        const float cb = (t == 0) ? 0.f : cumB[b];
        const int   hd = (t == 0) ? 0   : halted[b];
        float w;
        if (hd) {
            w = 0.f;
        } else if (cb + p >= 0.99f || t == TMAX - 1) {
            w = 1.f - cb;                 // remainder R
            halted[b] = 1;
            Rv[b] = w;
            nstep[b] = (float)t;
        } else {
            w = p;
            cumB[b] = cb + p;
            if (t == 0) halted[b] = 0;
        }
        w_sh = w;
        if (t == TMAX - 1) ponder[b] = nstep[b] + 1.f + Rv[b];
    }
    __syncthreads();
    const float w = w_sh;
    if (t > 0 && w == 0.f) return;        // halted rows contribute nothing

    float* hrow = hidden + (size_t)b * H_SZ;
    if (t == 0) {
        float4 h0 = make_float4(w * s0.x, w * s0.y, w * s0.z, w * s0.w);
        float4 h1 = make_float4(w * s1.x, w * s1.y, w * s1.z, w * s1.w);
        *(float4*)(hrow + tid * 8)     = h0;
        *(float4*)(hrow + tid * 8 + 4) = h1;
    } else {
        float4 h0 = *(const float4*)(hrow + tid * 8);
        float4 h1 = *(const float4*)(hrow + tid * 8 + 4);
        h0.x += w * s0.x; h0.y += w * s0.y; h0.z += w * s0.z; h0.w += w * s0.w;
        h1.x += w * s1.x; h1.y += w * s1.y; h1.z += w * s1.z; h1.w += w * s1.w;
        *(float4*)(hrow + tid * 8)     = h0;
        *(float4*)(hrow + tid * 8 + 4) = h1;
    }
}

extern "C" void kernel_launch(void* const* d_in, const int* in_sizes, int n_in,
                              void* d_out, int out_size, void* d_ws, size_t ws_size,
                              hipStream_t stream)
{
    const float* x        = (const float*)d_in[0];   // [B, D_IN]
    const float* h        = (const float*)d_in[1];   // [B, H]
    const float* W_hidden = (const float*)d_in[2];   // [H, D_IN+H]
    const float* b_hidden = (const float*)d_in[3];   // [H]
    const float* w_halt   = (const float*)d_in[4];   // [H]
    const float* b_halt   = (const float*)d_in[5];   // [1]
    const float* W_out    = (const float*)d_in[6];   // [D_OUT, H]
    const float* b_out    = (const float*)d_in[7];   // [D_OUT]

    float* out    = (float*)d_out;
    float* output = out;                                   // [B, D_OUT]
    float* hidden = out + (size_t)B_SZ * D_OUTN;           // [B, H]
    float* ponder = hidden + (size_t)B_SZ * H_SZ;          // [B]

    float* ws    = (float*)d_ws;
    float* xc    = ws;                                     // [B, H]
    float* sbuf0 = xc + (size_t)B_SZ * H_SZ;               // [B, H]
    float* sbuf1 = sbuf0 + (size_t)B_SZ * H_SZ;            // [B, H]
    float* rsum  = sbuf1 + (size_t)B_SZ * H_SZ;            // [H]
    float* cumB  = rsum + H_SZ;                            // [B]
    float* Rv    = cumB + B_SZ;                            // [B]
    float* nstep = Rv + B_SZ;                              // [B]
    int*   halted = (int*)(nstep + B_SZ);                  // [B]

    const dim3 blk(256);
    const int LDW = D_INN + H_SZ;  // 3072

    // xc = x @ W_x^T + b_hidden   (W_x = W_hidden[:, :D_IN])
    gemm_nt<<<dim3(H_SZ / BN, B_SZ / BM), blk, 0, stream>>>(
        x, D_INN, W_hidden, LDW, nullptr, b_hidden, xc, H_SZ, D_INN);

    // rsum[j] = sum_k W_x[j,k]   (correction for xin = x+1 at t==0)
    rowsum_kernel<<<dim3(H_SZ), blk, 0, stream>>>(W_hidden, LDW, D_INN, rsum);

    const float* s_prev = h;
    for (int t = 0; t < TMAX; ++t) {
        float* s_new = (t & 1) ? sbuf1 : sbuf0;
        // s_new = s_prev @ W_s^T + xc (+ rsum at t==0)   (W_s = W_hidden[:, D_IN:])
        gemm_nt<<<dim3(H_SZ / BN, B_SZ / BM), blk, 0, stream>>>(
            s_prev, H_SZ, W_hidden + D_INN, LDW,
            xc, (t == 0) ? rsum : nullptr, s_new, H_SZ, H_SZ);
        halt_accum<<<dim3(B_SZ), blk, 0, stream>>>(
            s_new, w_halt, b_halt, hidden, ponder, cumB, Rv, nstep, halted, t);
        s_prev = s_new;
    }

    // output = hidden @ W_out^T + b_out   (Σw = 1 ⇒ out-projection commutes with the ACT sum)
    gemm_nt<<<dim3(D_OUTN / BN, B_SZ / BM), blk, 0, stream>>>(
        hidden, H_SZ, W_out, H_SZ, nullptr, b_out, output, D_OUTN, H_SZ);
}

// Round 3
// 1587.014 us; speedup vs baseline: 1.8984x; 1.8984x over previous
//
#include <hip/hip_runtime.h>
#include <hip/hip_bf16.h>
#include <cstdint>

#define B_SZ   2048
#define D_INN  1024
#define H_SZ   2048
#define D_OUTN 1024
#define TMAX   12

typedef _Float16 f16;
typedef __attribute__((ext_vector_type(8))) _Float16 f16x8;
typedef __attribute__((ext_vector_type(4))) _Float16 f16x4;
typedef __attribute__((ext_vector_type(4))) float    f32x4;

typedef const __attribute__((address_space(1))) uint32_t* gptr_t;
typedef __attribute__((address_space(3))) uint32_t*       lptr_t;
__device__ inline void gld16(const void* g, void* l) {   // 16B global->LDS DMA
    __builtin_amdgcn_global_load_lds((gptr_t)g, (lptr_t)l, 16, 0, 0);
}

// ---------------------------------------------------------------------------
// Split-fp16 NT GEMM: C = A·B^T in ~fp32 precision via 3-term Markidis:
//   A = Ahi+Alo, B = Bhi+Blo;  C ≈ Ahi·Bhi + Ahi·Blo + Alo·Bhi   (fp32 accum)
// A [M,K], B [N,K] fp16 row-major. 128x128 tile, BK=32, 256 thr (4 waves),
// mfma_f32_16x16x32_f16, global_load_lds staging (m97 structure).
// Epilogue: +Cadd (fp32), +radd; writes Cf (fp32) and/or (Chi, Clo) fp16 pair.
// ---------------------------------------------------------------------------
__global__ __launch_bounds__(256) void gemm_split(
    const f16* __restrict__ Ahi, const f16* __restrict__ Alo, int lda,
    const f16* __restrict__ Bhi, const f16* __restrict__ Blo, int ldb,
    const float* __restrict__ Cadd,   // optional [M,ldc] fp32
    const float* __restrict__ radd,   // optional [N] fp32
    float* __restrict__ Cf,           // optional fp32 out
    f16* __restrict__ Chi, f16* __restrict__ Clo,  // optional fp16 pair out
    int ldc, int K)
{
    __shared__ __align__(16) f16 Ash[128 * 32];
    __shared__ __align__(16) f16 Asl[128 * 32];
    __shared__ __align__(16) f16 Bsh[128 * 32];
    __shared__ __align__(16) f16 Bsl[128 * 32];
    const int tid  = threadIdx.x;
    const int wave = tid >> 6;
    const int lane = tid & 63;
    const int m0 = blockIdx.y * 128, n0 = blockIdx.x * 128;
    const int wr = wave >> 1, wc = wave & 1;      // wave -> 64x64 quadrant
    const int fr = lane & 15, fq = lane >> 4;     // fragment row / k-group

    // staging: thread tid loads 16B (8 f16) at row tid>>2, cols (tid&3)*8
    const int srow = tid >> 2;
    const int scol = (tid & 3) * 8;
    const size_t aoff = (size_t)(m0 + srow) * lda + scol;
    const size_t boff = (size_t)(n0 + srow) * ldb + scol;
    const f16* gAh = Ahi + aoff;
    const f16* gAl = Alo + aoff;
    const f16* gBh = Bhi + boff;
    const f16* gBl = Blo + boff;
    f16* lAh = Ash + wave * 512;   // wave-uniform base, lane x 16B linear
    f16* lAl = Asl + wave * 512;
    f16* lBh = Bsh + wave * 512;
    f16* lBl = Bsl + wave * 512;

    f32x4 acc[4][4] = {};

    for (int k0 = 0; k0 < K; k0 += 32) {
        __syncthreads();
        gld16(gAh + k0,                    lAh);
        gld16(gAh + (size_t)64 * lda + k0, lAh + 2048);
        gld16(gAl + k0,                    lAl);
        gld16(gAl + (size_t)64 * lda + k0, lAl + 2048);
        gld16(gBh + k0,                    lBh);
        gld16(gBh + (size_t)64 * ldb + k0, lBh + 2048);
        gld16(gBl + k0,                    lBl);
        gld16(gBl + (size_t)64 * ldb + k0, lBl + 2048);
        __syncthreads();   // compiler drains vmcnt before s_barrier

        f16x8 ah[4], al[4], bh[4], bl[4];
#pragma unroll
        for (int m = 0; m < 4; ++m) {
            const int ro = (wr * 64 + m * 16 + fr) * 32 + fq * 8;
            ah[m] = *(const f16x8*)(Ash + ro);
            al[m] = *(const f16x8*)(Asl + ro);
        }
#pragma unroll
        for (int n = 0; n < 4; ++n) {
            const int ro = (wc * 64 + n * 16 + fr) * 32 + fq * 8;
            bh[n] = *(const f16x8*)(Bsh + ro);
            bl[n] = *(const f16x8*)(Bsl + ro);
        }
#pragma unroll
        for (int m = 0; m < 4; ++m)
#pragma unroll
            for (int n = 0; n < 4; ++n)
                acc[m][n] = __builtin_amdgcn_mfma_f32_16x16x32_f16(
                    ah[m], bh[n], acc[m][n], 0, 0, 0);
#pragma unroll
        for (int m = 0; m < 4; ++m)
#pragma unroll
            for (int n = 0; n < 4; ++n)
                acc[m][n] = __builtin_amdgcn_mfma_f32_16x16x32_f16(
                    ah[m], bl[n], acc[m][n], 0, 0, 0);
#pragma unroll
        for (int m = 0; m < 4; ++m)
#pragma unroll
            for (int n = 0; n < 4; ++n)
                acc[m][n] = __builtin_amdgcn_mfma_f32_16x16x32_f16(
                    al[m], bh[n], acc[m][n], 0, 0, 0);
    }

    // C/D layout: col = lane&15, row = (lane>>4)*4 + reg   [m89/m91 verified]
#pragma unroll
    for (int m = 0; m < 4; ++m) {
#pragma unroll
        for (int n = 0; n < 4; ++n) {
#pragma unroll
            for (int r = 0; r < 4; ++r) {
                const int row = m0 + wr * 64 + m * 16 + fq * 4 + r;
                const int col = n0 + wc * 64 + n * 16 + fr;
                float v = acc[m][n][r];
                if (Cadd) v += Cadd[(size_t)row * ldc + col];
                if (radd) v += radd[col];
                if (Cf) Cf[(size_t)row * ldc + col] = v;
                if (Chi) {
                    const f16 hi = (f16)v;
                    Chi[(size_t)row * ldc + col] = hi;
                    Clo[(size_t)row * ldc + col] = (f16)(v - (float)hi);
                }
            }
        }
    }
}

// strided fp32 [rows,cols] (ld) -> contiguous fp16 (hi, lo) pair
__global__ __launch_bounds__(256) void split2d(
    const float* __restrict__ src, int ld, int cols,
    f16* __restrict__ hi, f16* __restrict__ lo, int total4)
{
    const int i = blockIdx.x * 256 + threadIdx.x;
    if (i >= total4) return;
    const int idx = i * 4;
    const int r = idx / cols, c = idx % cols;
    const float4 v = *(const float4*)(src + (size_t)r * ld + c);
    f16x4 h, l;
    h[0] = (f16)v.x; l[0] = (f16)(v.x - (float)h[0]);
    h[1] = (f16)v.y; l[1] = (f16)(v.y - (float)h[1]);
    h[2] = (f16)v.z; l[2] = (f16)(v.z - (float)h[2]);
    h[3] = (f16)v.w; l[3] = (f16)(v.w - (float)h[3]);
    *(f16x4*)(hi + idx) = h;
    *(f16x4*)(lo + idx) = l;
}

// rsum[j] = sum_{k<K} W[j,k]   (the (x+1)-vs-x correction for t==0), fp32
__global__ __launch_bounds__(256) void rowsum_kernel(
    const float* __restrict__ W, int ld, int K, float* __restrict__ out)
{
    const int j = blockIdx.x;
    const int tid = threadIdx.x;
    float s = 0.f;
    for (int k = tid; k < K; k += 256) s += W[(size_t)j * ld + k];
#pragma unroll
    for (int off = 32; off; off >>= 1) s += __shfl_down(s, off);
    __shared__ float red[4];
    if ((tid & 63) == 0) red[tid >> 6] = s;
    __syncthreads();
    if (tid == 0) out[j] = red[0] + red[1] + red[2] + red[3];
}

// Per-step ACT halting + weighted accumulation of hidden. 1 block / row.
// s reconstructed as hi+lo (error ~2^-22 rel) so halting decisions match fp32.
__global__ __launch_bounds__(256) void halt_accum(
    const f16* __restrict__ s_hi, const f16* __restrict__ s_lo,  // [B,H]
    const float* __restrict__ w_halt,  // [H]
    const float* __restrict__ b_halt,  // [1]
    float* __restrict__ hidden,        // [B,H] accumulator (in d_out)
    float* __restrict__ ponder,        // [B]   (in d_out)
    float* __restrict__ cumB,          // [B] state
    float* __restrict__ Rv,            // [B] state
    float* __restrict__ nstep,         // [B] state
    int*   __restrict__ halted,        // [B] state
    int t)
{
    const int b = blockIdx.x;
    const int tid = threadIdx.x;
    const f16x8 vh = *(const f16x8*)(s_hi + (size_t)b * H_SZ + tid * 8);
    const f16x8 vl = *(const f16x8*)(s_lo + (size_t)b * H_SZ + tid * 8);
    float s[8];
#pragma unroll
    for (int j = 0; j < 8; ++j) s[j] = (float)vh[j] + (float)vl[j];
    const float4 w0 = *(const float4*)(w_halt + tid * 8);
    const float4 w1 = *(const float4*)(w_halt + tid * 8 + 4);
    float part = s[0] * w0.x + s[1] * w0.y + s[2] * w0.z + s[3] * w0.w
               + s[4] * w1.x + s[5] * w1.y + s[6] * w1.z + s[7] * w1.w;
#pragma unroll
    for (int off = 32; off; off >>= 1) part += __shfl_down(part, off);

    __shared__ float red[4];
    __shared__ float w_sh;
    if ((tid & 63) == 0) red[tid >> 6] = part;
    __syncthreads();
    if (tid == 0) {
        const float dot = red[0] + red[1] + red[2] + red[3] + b_halt[0];
        const float p = 1.f / (1.f + expf(-dot));
        const float cb = (t == 0) ? 0.f : cumB[b];
        const int   hd = (t == 0) ? 0   : halted[b];
        float w;
        if (hd) {
            w = 0.f;
        } else if (cb + p >= 0.99f || t == TMAX - 1) {
            w = 1.f - cb;                 // remainder R
            halted[b] = 1;
            Rv[b] = w;
            nstep[b] = (float)t;
        } else {
            w = p;
            cumB[b] = cb + p;
            if (t == 0) halted[b] = 0;
        }
        w_sh = w;
        if (t == TMAX - 1) ponder[b] = nstep[b] + 1.f + Rv[b];
    }
    __syncthreads();
    const float w = w_sh;
    if (t > 0 && w == 0.f) return;        // halted rows contribute nothing

    float* hrow = hidden + (size_t)b * H_SZ + tid * 8;
    if (t == 0) {
#pragma unroll
        for (int j = 0; j < 8; ++j) hrow[j] = w * s[j];
    } else {
        float4 h0 = *(const float4*)(hrow);
        float4 h1 = *(const float4*)(hrow + 4);
        h0.x += w * s[0]; h0.y += w * s[1]; h0.z += w * s[2]; h0.w += w * s[3];
        h1.x += w * s[4]; h1.y += w * s[5]; h1.z += w * s[6]; h1.w += w * s[7];
        *(float4*)(hrow)     = h0;
        *(float4*)(hrow + 4) = h1;
    }
}

extern "C" void kernel_launch(void* const* d_in, const int* in_sizes, int n_in,
                              void* d_out, int out_size, void* d_ws, size_t ws_size,
                              hipStream_t stream)
{
    const float* x        = (const float*)d_in[0];   // [B, D_IN]
    const float* h        = (const float*)d_in[1];   // [B, H]
    const float* W_hidden = (const float*)d_in[2];   // [H, D_IN+H]
    const float* b_hidden = (const float*)d_in[3];   // [H]
    const float* w_halt   = (const float*)d_in[4];   // [H]
    const float* b_halt   = (const float*)d_in[5];   // [1]
    const float* W_out    = (const float*)d_in[6];   // [D_OUT, H]
    const float* b_out    = (const float*)d_in[7];   // [D_OUT]

    float* out    = (float*)d_out;
    float* output = out;                                   // [B, D_OUT]
    float* hidden = out + (size_t)B_SZ * D_OUTN;           // [B, H]
    float* ponder = hidden + (size_t)B_SZ * H_SZ;          // [B]

    // ---- workspace layout ----
    float* ws     = (float*)d_ws;
    float* xc     = ws;                                    // [B,H] fp32 16MB
    float* rsum   = xc + (size_t)B_SZ * H_SZ;              // [H]
    float* cumB   = rsum + H_SZ;                           // [B]
    float* Rv     = cumB + B_SZ;                           // [B]
    float* nstep  = Rv + B_SZ;                             // [B]
    int*   halted = (int*)(nstep + B_SZ);                  // [B]
    f16*   fh     = (f16*)(halted + B_SZ);
    f16* xh  = fh;                         // [B,D_IN]  4MB
    f16* xl  = xh  + (size_t)B_SZ * D_INN; // 4MB
    f16* sh0 = xl  + (size_t)B_SZ * D_INN; // [B,H] 8MB
    f16* sl0 = sh0 + (size_t)B_SZ * H_SZ;
    f16* sh1 = sl0 + (size_t)B_SZ * H_SZ;
    f16* sl1 = sh1 + (size_t)B_SZ * H_SZ;
    f16* Wxh = sl1 + (size_t)B_SZ * H_SZ;  // [H,D_IN] 4MB
    f16* Wxl = Wxh + (size_t)H_SZ * D_INN;
    f16* Wsh = Wxl + (size_t)H_SZ * D_INN; // [H,H] 8MB
    f16* Wsl = Wsh + (size_t)H_SZ * H_SZ;
    f16* Woh = Wsl + (size_t)H_SZ * H_SZ;  // [D_OUT,H] 4MB
    f16* Wol = Woh + (size_t)D_OUTN * H_SZ;
    f16* hidh = sh0;                       // reuse after the t-loop
    f16* hidl = sl0;

    const dim3 blk(256);
    const int LDW = D_INN + H_SZ;  // 3072

    // one-time fp32 -> fp16 (hi,lo) splits
    split2d<<<dim3(B_SZ * D_INN / 4 / 256), blk, 0, stream>>>(
        x, D_INN, D_INN, xh, xl, B_SZ * D_INN / 4);
    split2d<<<dim3(B_SZ * H_SZ / 4 / 256), blk, 0, stream>>>(
        h, H_SZ, H_SZ, sh0, sl0, B_SZ * H_SZ / 4);
    split2d<<<dim3(H_SZ * D_INN / 4 / 256), blk, 0, stream>>>(
        W_hidden, LDW, D_INN, Wxh, Wxl, H_SZ * D_INN / 4);
    split2d<<<dim3(H_SZ * H_SZ / 4 / 256), blk, 0, stream>>>(
        W_hidden + D_INN, LDW, H_SZ, Wsh, Wsl, H_SZ * H_SZ / 4);
    split2d<<<dim3(D_OUTN * H_SZ / 4 / 256), blk, 0, stream>>>(
        W_out, H_SZ, H_SZ, Woh, Wol, D_OUTN * H_SZ / 4);

    // rsum[j] = sum_k W_x[j,k]   (xin = x+1 correction at t==0)
    rowsum_kernel<<<dim3(H_SZ), blk, 0, stream>>>(W_hidden, LDW, D_INN, rsum);

    // xc = x @ W_x^T + b_hidden   (loop-invariant part, fp32)
    gemm_split<<<dim3(H_SZ / 128, B_SZ / 128), blk, 0, stream>>>(
        xh, xl, D_INN, Wxh, Wxl, D_INN, nullptr, b_hidden,
        xc, nullptr, nullptr, H_SZ, D_INN);

    for (int t = 0; t < TMAX; ++t) {
        const f16* ph = (t & 1) ? sh1 : sh0;
        const f16* pl = (t & 1) ? sl1 : sl0;
        f16*       nh = (t & 1) ? sh0 : sh1;
        f16*       nl = (t & 1) ? sl0 : sl1;
        // s_new = s_prev @ W_s^T + xc (+ rsum at t==0), written as (hi,lo)
        gemm_split<<<dim3(H_SZ / 128, B_SZ / 128), blk, 0, stream>>>(
            ph, pl, H_SZ, Wsh, Wsl, H_SZ, xc, (t == 0) ? rsum : nullptr,
            nullptr, nh, nl, H_SZ, H_SZ);
        halt_accum<<<dim3(B_SZ), blk, 0, stream>>>(
            nh, nl, w_halt, b_halt, hidden, ponder, cumB, Rv, nstep, halted, t);
    }

    // output = hidden @ W_out^T + b_out   (Σw = 1 ⇒ projection commutes)
    split2d<<<dim3(B_SZ * H_SZ / 4 / 256), blk, 0, stream>>>(
        hidden, H_SZ, H_SZ, hidh, hidl, B_SZ * H_SZ / 4);
    gemm_split<<<dim3(D_OUTN / 128, B_SZ / 128), blk, 0, stream>>>(
        hidh, hidl, H_SZ, Woh, Wol, H_SZ, nullptr, b_out,
        output, nullptr, nullptr, D_OUTN, H_SZ);
}

// Round 4
// 1553.093 us; speedup vs baseline: 1.9399x; 1.0218x over previous
//
#include <hip/hip_runtime.h>
#include <hip/hip_bf16.h>
#include <cstdint>

#define B_SZ   2048
#define D_INN  1024
#define H_SZ   2048
#define D_OUTN 1024
#define TMAX   12

typedef _Float16 f16;
typedef __attribute__((ext_vector_type(8))) _Float16 f16x8;
typedef __attribute__((ext_vector_type(4))) _Float16 f16x4;
typedef __attribute__((ext_vector_type(4))) float    f32x4;

typedef const __attribute__((address_space(1))) uint32_t* gptr_t;
typedef __attribute__((address_space(3))) uint32_t*       lptr_t;
__device__ inline void gld16(const void* g, void* l) {   // 16B global->LDS DMA
    __builtin_amdgcn_global_load_lds((gptr_t)g, (lptr_t)l, 16, 0, 0);
}

// ---------------------------------------------------------------------------
// Split-fp16 NT GEMM: C = A·B^T in ~fp32 precision via 3-term Markidis:
//   A = Ahi+Alo, B = Bhi+Blo;  C ≈ Ahi·Bhi + Ahi·Blo + Alo·Bhi   (fp32 accum)
// A [M,K], B [N,K] fp16 row-major. 128x128 tile, BK=32, 256 thr (4 waves),
// mfma_f32_16x16x32_f16.  T3 2-phase pipeline: double-buffered LDS,
// STAGE(next) issued before compute(cur), ONE __syncthreads per K-step
// (its auto vmcnt(0) drains the prefetch AFTER compute has covered it).
// Epilogue: +Cadd (fp32), +radd; writes Cf (fp32) and/or (Chi, Clo) fp16 pair.
// ---------------------------------------------------------------------------
__global__ __launch_bounds__(256) void gemm_split(
    const f16* __restrict__ Ahi, const f16* __restrict__ Alo, int lda,
    const f16* __restrict__ Bhi, const f16* __restrict__ Blo, int ldb,
    const float* __restrict__ Cadd,   // optional [M,ldc] fp32
    const float* __restrict__ radd,   // optional [N] fp32
    float* __restrict__ Cf,           // optional fp32 out
    f16* __restrict__ Chi, f16* __restrict__ Clo,  // optional fp16 pair out
    int ldc, int K)
{
    __shared__ __align__(16) f16 Ash[2][128 * 32];
    __shared__ __align__(16) f16 Asl[2][128 * 32];
    __shared__ __align__(16) f16 Bsh[2][128 * 32];
    __shared__ __align__(16) f16 Bsl[2][128 * 32];
    const int tid  = threadIdx.x;
    const int wave = tid >> 6;
    const int lane = tid & 63;
    const int m0 = blockIdx.y * 128, n0 = blockIdx.x * 128;
    const int wr = wave >> 1, wc = wave & 1;      // wave -> 64x64 quadrant
    const int fr = lane & 15, fq = lane >> 4;     // fragment row / k-group

    // staging: thread tid loads 16B (8 f16) at row tid>>2, cols (tid&3)*8
    const int srow = tid >> 2;
    const int scol = (tid & 3) * 8;
    const size_t aoff = (size_t)(m0 + srow) * lda + scol;
    const size_t boff = (size_t)(n0 + srow) * ldb + scol;
    const f16* gAh = Ahi + aoff;
    const f16* gAl = Alo + aoff;
    const f16* gBh = Bhi + boff;
    const f16* gBl = Blo + boff;
    const int lofs = wave * 512;   // wave-uniform base (lane x 16B linear)

    f32x4 acc[4][4] = {};

    // prologue: stage tile 0 into buffer 0, full drain once
    {
        gld16(gAh,                    &Ash[0][lofs]);
        gld16(gAh + (size_t)64 * lda, &Ash[0][lofs + 2048]);
        gld16(gAl,                    &Asl[0][lofs]);
        gld16(gAl + (size_t)64 * lda, &Asl[0][lofs + 2048]);
        gld16(gBh,                    &Bsh[0][lofs]);
        gld16(gBh + (size_t)64 * ldb, &Bsh[0][lofs + 2048]);
        gld16(gBl,                    &Bsl[0][lofs]);
        gld16(gBl + (size_t)64 * ldb, &Bsl[0][lofs + 2048]);
        __syncthreads();
    }

    int cur = 0;
    for (int k0 = 0; k0 < K; k0 += 32) {
        // issue next-tile loads first — they fly under this tile's compute
        if (k0 + 32 < K) {
            const int nk = k0 + 32;
            const int nb = cur ^ 1;
            gld16(gAh + nk,                    &Ash[nb][lofs]);
            gld16(gAh + (size_t)64 * lda + nk, &Ash[nb][lofs + 2048]);
            gld16(gAl + nk,                    &Asl[nb][lofs]);
            gld16(gAl + (size_t)64 * lda + nk, &Asl[nb][lofs + 2048]);
            gld16(gBh + nk,                    &Bsh[nb][lofs]);
            gld16(gBh + (size_t)64 * ldb + nk, &Bsh[nb][lofs + 2048]);
            gld16(gBl + nk,                    &Bsl[nb][lofs]);
            gld16(gBl + (size_t)64 * ldb + nk, &Bsl[nb][lofs + 2048]);
        }

        f16x8 ah[4], al[4], bh[4], bl[4];
#pragma unroll
        for (int m = 0; m < 4; ++m) {
            const int ro = (wr * 64 + m * 16 + fr) * 32 + fq * 8;
            ah[m] = *(const f16x8*)(&Ash[cur][ro]);
            al[m] = *(const f16x8*)(&Asl[cur][ro]);
        }
#pragma unroll
        for (int n = 0; n < 4; ++n) {
            const int ro = (wc * 64 + n * 16 + fr) * 32 + fq * 8;
            bh[n] = *(const f16x8*)(&Bsh[cur][ro]);
            bl[n] = *(const f16x8*)(&Bsl[cur][ro]);
        }
#pragma unroll
        for (int m = 0; m < 4; ++m)
#pragma unroll
            for (int n = 0; n < 4; ++n)
                acc[m][n] = __builtin_amdgcn_mfma_f32_16x16x32_f16(
                    ah[m], bh[n], acc[m][n], 0, 0, 0);
#pragma unroll
        for (int m = 0; m < 4; ++m)
#pragma unroll
            for (int n = 0; n < 4; ++n)
                acc[m][n] = __builtin_amdgcn_mfma_f32_16x16x32_f16(
                    ah[m], bl[n], acc[m][n], 0, 0, 0);
#pragma unroll
        for (int m = 0; m < 4; ++m)
#pragma unroll
            for (int n = 0; n < 4; ++n)
                acc[m][n] = __builtin_amdgcn_mfma_f32_16x16x32_f16(
                    al[m], bh[n], acc[m][n], 0, 0, 0);

        // one barrier per K-step: auto vmcnt(0) drains the prefetch (which has
        // been in flight across 48 MFMAs) and fences LDS reuse across waves.
        __syncthreads();
        cur ^= 1;
    }

    // C/D layout: col = lane&15, row = (lane>>4)*4 + reg   [m89/m91 verified]
#pragma unroll
    for (int m = 0; m < 4; ++m) {
#pragma unroll
        for (int n = 0; n < 4; ++n) {
#pragma unroll
            for (int r = 0; r < 4; ++r) {
                const int row = m0 + wr * 64 + m * 16 + fq * 4 + r;
                const int col = n0 + wc * 64 + n * 16 + fr;
                float v = acc[m][n][r];
                if (Cadd) v += Cadd[(size_t)row * ldc + col];
                if (radd) v += radd[col];
                if (Cf) Cf[(size_t)row * ldc + col] = v;
                if (Chi) {
                    const f16 hi = (f16)v;
                    Chi[(size_t)row * ldc + col] = hi;
                    Clo[(size_t)row * ldc + col] = (f16)(v - (float)hi);
                }
            }
        }
    }
}

// strided fp32 [rows,cols] (ld) -> contiguous fp16 (hi, lo) pair
__global__ __launch_bounds__(256) void split2d(
    const float* __restrict__ src, int ld, int cols,
    f16* __restrict__ hi, f16* __restrict__ lo, int total4)
{
    const int i = blockIdx.x * 256 + threadIdx.x;
    if (i >= total4) return;
    const int idx = i * 4;
    const int r = idx / cols, c = idx % cols;
    const float4 v = *(const float4*)(src + (size_t)r * ld + c);
    f16x4 h, l;
    h[0] = (f16)v.x; l[0] = (f16)(v.x - (float)h[0]);
    h[1] = (f16)v.y; l[1] = (f16)(v.y - (float)h[1]);
    h[2] = (f16)v.z; l[2] = (f16)(v.z - (float)h[2]);
    h[3] = (f16)v.w; l[3] = (f16)(v.w - (float)h[3]);
    *(f16x4*)(hi + idx) = h;
    *(f16x4*)(lo + idx) = l;
}

// rsum[j] = sum_{k<K} W[j,k]   (the (x+1)-vs-x correction for t==0), fp32
__global__ __launch_bounds__(256) void rowsum_kernel(
    const float* __restrict__ W, int ld, int K, float* __restrict__ out)
{
    const int j = blockIdx.x;
    const int tid = threadIdx.x;
    float s = 0.f;
    for (int k = tid; k < K; k += 256) s += W[(size_t)j * ld + k];
#pragma unroll
    for (int off = 32; off; off >>= 1) s += __shfl_down(s, off);
    __shared__ float red[4];
    if ((tid & 63) == 0) red[tid >> 6] = s;
    __syncthreads();
    if (tid == 0) out[j] = red[0] + red[1] + red[2] + red[3];
}

// Per-step ACT halting + weighted accumulation of hidden. 1 block / row.
// s reconstructed as hi+lo (error ~2^-22 rel) so halting decisions match fp32.
__global__ __launch_bounds__(256) void halt_accum(
    const f16* __restrict__ s_hi, const f16* __restrict__ s_lo,  // [B,H]
    const float* __restrict__ w_halt,  // [H]
    const float* __restrict__ b_halt,  // [1]
    float* __restrict__ hidden,        // [B,H] accumulator (in d_out)
    float* __restrict__ ponder,        // [B]   (in d_out)
    float* __restrict__ cumB,          // [B] state
    float* __restrict__ Rv,            // [B] state
    float* __restrict__ nstep,         // [B] state
    int*   __restrict__ halted,        // [B] state
    int t)
{
    const int b = blockIdx.x;
    const int tid = threadIdx.x;
    const f16x8 vh = *(const f16x8*)(s_hi + (size_t)b * H_SZ + tid * 8);
    const f16x8 vl = *(const f16x8*)(s_lo + (size_t)b * H_SZ + tid * 8);
    float s[8];
#pragma unroll
    for (int j = 0; j < 8; ++j) s[j] = (float)vh[j] + (float)vl[j];
    const float4 w0 = *(const float4*)(w_halt + tid * 8);
    const float4 w1 = *(const float4*)(w_halt + tid * 8 + 4);
    float part = s[0] * w0.x + s[1] * w0.y + s[2] * w0.z + s[3] * w0.w
               + s[4] * w1.x + s[5] * w1.y + s[6] * w1.z + s[7] * w1.w;
#pragma unroll
    for (int off = 32; off; off >>= 1) part += __shfl_down(part, off);

    __shared__ float red[4];
    __shared__ float w_sh;
    if ((tid & 63) == 0) red[tid >> 6] = part;
    __syncthreads();
    if (tid == 0) {
        const float dot = red[0] + red[1] + red[2] + red[3] + b_halt[0];
        const float p = 1.f / (1.f + expf(-dot));
        const float cb = (t == 0) ? 0.f : cumB[b];
        const int   hd = (t == 0) ? 0   : halted[b];
        float w;
        if (hd) {
            w = 0.f;
        } else if (cb + p >= 0.99f || t == TMAX - 1) {
            w = 1.f - cb;                 // remainder R
            halted[b] = 1;
            Rv[b] = w;
            nstep[b] = (float)t;
        } else {
            w = p;
            cumB[b] = cb + p;
            if (t == 0) halted[b] = 0;
        }
        w_sh = w;
        if (t == TMAX - 1) ponder[b] = nstep[b] + 1.f + Rv[b];
    }
    __syncthreads();
    const float w = w_sh;
    if (t > 0 && w == 0.f) return;        // halted rows contribute nothing

    float* hrow = hidden + (size_t)b * H_SZ + tid * 8;
    if (t == 0) {
#pragma unroll
        for (int j = 0; j < 8; ++j) hrow[j] = w * s[j];
    } else {
        float4 h0 = *(const float4*)(hrow);
        float4 h1 = *(const float4*)(hrow + 4);
        h0.x += w * s[0]; h0.y += w * s[1]; h0.z += w * s[2]; h0.w += w * s[3];
        h1.x += w * s[4]; h1.y += w * s[5]; h1.z += w * s[6]; h1.w += w * s[7];
        *(float4*)(hrow)     = h0;
        *(float4*)(hrow + 4) = h1;
    }
}

extern "C" void kernel_launch(void* const* d_in, const int* in_sizes, int n_in,
                              void* d_out, int out_size, void* d_ws, size_t ws_size,
                              hipStream_t stream)
{
    const float* x        = (const float*)d_in[0];   // [B, D_IN]
    const float* h        = (const float*)d_in[1];   // [B, H]
    const float* W_hidden = (const float*)d_in[2];   // [H, D_IN+H]
    const float* b_hidden = (const float*)d_in[3];   // [H]
    const float* w_halt   = (const float*)d_in[4];   // [H]
    const float* b_halt   = (const float*)d_in[5];   // [1]
    const float* W_out    = (const float*)d_in[6];   // [D_OUT, H]
    const float* b_out    = (const float*)d_in[7];   // [D_OUT]

    float* out    = (float*)d_out;
    float* output = out;                                   // [B, D_OUT]
    float* hidden = out + (size_t)B_SZ * D_OUTN;           // [B, H]
    float* ponder = hidden + (size_t)B_SZ * H_SZ;          // [B]

    // ---- workspace layout ----
    float* ws     = (float*)d_ws;
    float* xc     = ws;                                    // [B,H] fp32 16MB
    float* rsum   = xc + (size_t)B_SZ * H_SZ;              // [H]
    float* cumB   = rsum + H_SZ;                           // [B]
    float* Rv     = cumB + B_SZ;                           // [B]
    float* nstep  = Rv + B_SZ;                             // [B]
    int*   halted = (int*)(nstep + B_SZ);                  // [B]
    f16*   fh     = (f16*)(halted + B_SZ);
    f16* xh  = fh;                         // [B,D_IN]  4MB
    f16* xl  = xh  + (size_t)B_SZ * D_INN; // 4MB
    f16* sh0 = xl  + (size_t)B_SZ * D_INN; // [B,H] 8MB
    f16* sl0 = sh0 + (size_t)B_SZ * H_SZ;
    f16* sh1 = sl0 + (size_t)B_SZ * H_SZ;
    f16* sl1 = sh1 + (size_t)B_SZ * H_SZ;
    f16* Wxh = sl1 + (size_t)B_SZ * H_SZ;  // [H,D_IN] 4MB
    f16* Wxl = Wxh + (size_t)H_SZ * D_INN;
    f16* Wsh = Wxl + (size_t)H_SZ * D_INN; // [H,H] 8MB
    f16* Wsl = Wsh + (size_t)H_SZ * H_SZ;
    f16* Woh = Wsl + (size_t)H_SZ * H_SZ;  // [D_OUT,H] 4MB
    f16* Wol = Woh + (size_t)D_OUTN * H_SZ;
    f16* hidh = sh0;                       // reuse after the t-loop
    f16* hidl = sl0;

    const dim3 blk(256);
    const int LDW = D_INN + H_SZ;  // 3072

    // one-time fp32 -> fp16 (hi,lo) splits
    split2d<<<dim3(B_SZ * D_INN / 4 / 256), blk, 0, stream>>>(
        x, D_INN, D_INN, xh, xl, B_SZ * D_INN / 4);
    split2d<<<dim3(B_SZ * H_SZ / 4 / 256), blk, 0, stream>>>(
        h, H_SZ, H_SZ, sh0, sl0, B_SZ * H_SZ / 4);
    split2d<<<dim3(H_SZ * D_INN / 4 / 256), blk, 0, stream>>>(
        W_hidden, LDW, D_INN, Wxh, Wxl, H_SZ * D_INN / 4);
    split2d<<<dim3(H_SZ * H_SZ / 4 / 256), blk, 0, stream>>>(
        W_hidden + D_INN, LDW, H_SZ, Wsh, Wsl, H_SZ * H_SZ / 4);
    split2d<<<dim3(D_OUTN * H_SZ / 4 / 256), blk, 0, stream>>>(
        W_out, H_SZ, H_SZ, Woh, Wol, D_OUTN * H_SZ / 4);

    // rsum[j] = sum_k W_x[j,k]   (xin = x+1 correction at t==0)
    rowsum_kernel<<<dim3(H_SZ), blk, 0, stream>>>(W_hidden, LDW, D_INN, rsum);

    // xc = x @ W_x^T + b_hidden   (loop-invariant part, fp32)
    gemm_split<<<dim3(H_SZ / 128, B_SZ / 128), blk, 0, stream>>>(
        xh, xl, D_INN, Wxh, Wxl, D_INN, nullptr, b_hidden,
        xc, nullptr, nullptr, H_SZ, D_INN);

    for (int t = 0; t < TMAX; ++t) {
        const f16* ph = (t & 1) ? sh1 : sh0;
        const f16* pl = (t & 1) ? sl1 : sl0;
        f16*       nh = (t & 1) ? sh0 : sh1;
        f16*       nl = (t & 1) ? sl0 : sl1;
        // s_new = s_prev @ W_s^T + xc (+ rsum at t==0), written as (hi,lo)
        gemm_split<<<dim3(H_SZ / 128, B_SZ / 128), blk, 0, stream>>>(
            ph, pl, H_SZ, Wsh, Wsl, H_SZ, xc, (t == 0) ? rsum : nullptr,
            nullptr, nh, nl, H_SZ, H_SZ);
        halt_accum<<<dim3(B_SZ), blk, 0, stream>>>(
            nh, nl, w_halt, b_halt, hidden, ponder, cumB, Rv, nstep, halted, t);
    }

    // output = hidden @ W_out^T + b_out   (Σw = 1 ⇒ projection commutes)
    split2d<<<dim3(B_SZ * H_SZ / 4 / 256), blk, 0, stream>>>(
        hidden, H_SZ, H_SZ, hidh, hidl, B_SZ * H_SZ / 4);
    gemm_split<<<dim3(D_OUTN / 128, B_SZ / 128), blk, 0, stream>>>(
        hidh, hidl, H_SZ, Woh, Wol, H_SZ, nullptr, b_out,
        output, nullptr, nullptr, D_OUTN, H_SZ);
}

// Round 5
// 1137.197 us; speedup vs baseline: 2.6493x; 1.3657x over previous
//
#include <hip/hip_runtime.h>
#include <hip/hip_bf16.h>
#include <cstdint>

#define B_SZ   2048
#define D_INN  1024
#define H_SZ   2048
#define D_OUTN 1024
#define TMAX   12

typedef _Float16 f16;
typedef __attribute__((ext_vector_type(8))) _Float16 f16x8;
typedef __attribute__((ext_vector_type(4))) _Float16 f16x4;
typedef __attribute__((ext_vector_type(4))) float    f32x4;

typedef const __attribute__((address_space(1))) uint32_t* gptr_t;
typedef __attribute__((address_space(3))) uint32_t*       lptr_t;
__device__ inline void gld16(const void* g, void* l) {   // 16B global->LDS DMA
    __builtin_amdgcn_global_load_lds((gptr_t)g, (lptr_t)l, 16, 0, 0);
}

// ---------------------------------------------------------------------------
// Split-fp16 NT GEMM: C = A·B^T in ~fp32 precision via 3-term Markidis:
//   A = Ahi+Alo, B = Bhi+Blo;  C ≈ Ahi·Bhi + Ahi·Blo + Alo·Bhi   (fp32 accum)
// A [M,K], B [N,K] fp16 row-major.
// Tile 64x128 (BM=64, BN=128), BK=32, 256 thr (4 waves, wave tile 32x64).
// Grid is 1-D, nwg = (M/64)*(N/128), XCD-chunked bijective swizzle (nwg%8==0).
// 2 blocks/CU co-resident (LDS 48KB/block) — co-residency hides the
// vmcnt(0)+barrier drain that stalled the 1-block/CU 128x128 version.
// Epilogue: +Cadd (fp32), +radd; writes Cf (fp32) and/or (Chi, Clo) fp16 pair.
// ---------------------------------------------------------------------------
__global__ __launch_bounds__(256) void gemm_split(
    const f16* __restrict__ Ahi, const f16* __restrict__ Alo, int lda,
    const f16* __restrict__ Bhi, const f16* __restrict__ Blo, int ldb,
    const float* __restrict__ Cadd,   // optional [M,ldc] fp32
    const float* __restrict__ radd,   // optional [N] fp32
    float* __restrict__ Cf,           // optional fp32 out
    f16* __restrict__ Chi, f16* __restrict__ Clo,  // optional fp16 pair out
    int ldc, int K, int nx)
{
    __shared__ __align__(16) f16 Ash[2][64 * 32];
    __shared__ __align__(16) f16 Asl[2][64 * 32];
    __shared__ __align__(16) f16 Bsh[2][128 * 32];
    __shared__ __align__(16) f16 Bsl[2][128 * 32];
    const int tid  = threadIdx.x;
    const int wave = tid >> 6;
    const int lane = tid & 63;

    // XCD-chunked bijective blockIdx swizzle (requires nwg % 8 == 0)
    const int nwg = gridDim.x;
    const int cpx = nwg >> 3;
    const int bid = (blockIdx.x & 7) * cpx + (blockIdx.x >> 3);
    const int m0 = (bid / nx) * 64, n0 = (bid % nx) * 128;

    const int wr = wave >> 1, wc = wave & 1;      // wave -> 32x64 sub-tile
    const int fr = lane & 15, fq = lane >> 4;     // fragment row / k-group

    // staging: thread tid covers row tid>>2, cols (tid&3)*8 (16B each)
    const int srow = tid >> 2;
    const int scol = (tid & 3) * 8;
    const f16* gAh = Ahi + (size_t)(m0 + srow) * lda + scol;
    const f16* gAl = Alo + (size_t)(m0 + srow) * lda + scol;
    const f16* gBh = Bhi + (size_t)(n0 + srow) * ldb + scol;
    const f16* gBl = Blo + (size_t)(n0 + srow) * ldb + scol;
    const int lofs = wave * 512;   // wave-uniform LDS base (lane x 16B linear)

    f32x4 acc[2][4] = {};

    // prologue: stage tile 0 into buffer 0, full drain once
    gld16(gAh,                    &Ash[0][lofs]);
    gld16(gAl,                    &Asl[0][lofs]);
    gld16(gBh,                    &Bsh[0][lofs]);
    gld16(gBh + (size_t)64 * ldb, &Bsh[0][lofs + 2048]);
    gld16(gBl,                    &Bsl[0][lofs]);
    gld16(gBl + (size_t)64 * ldb, &Bsl[0][lofs + 2048]);
    __syncthreads();

    int cur = 0;
    for (int k0 = 0; k0 < K; k0 += 32) {
        // issue next-tile loads first — they fly under this tile's compute
        if (k0 + 32 < K) {
            const int nk = k0 + 32;
            const int nb = cur ^ 1;
            gld16(gAh + nk,                    &Ash[nb][lofs]);
            gld16(gAl + nk,                    &Asl[nb][lofs]);
            gld16(gBh + nk,                    &Bsh[nb][lofs]);
            gld16(gBh + (size_t)64 * ldb + nk, &Bsh[nb][lofs + 2048]);
            gld16(gBl + nk,                    &Bsl[nb][lofs]);
            gld16(gBl + (size_t)64 * ldb + nk, &Bsl[nb][lofs + 2048]);
        }

        f16x8 ah[2], al[2], bh[4], bl[4];
#pragma unroll
        for (int m = 0; m < 2; ++m) {
            const int ro = (wr * 32 + m * 16 + fr) * 32 + fq * 8;
            ah[m] = *(const f16x8*)(&Ash[cur][ro]);
            al[m] = *(const f16x8*)(&Asl[cur][ro]);
        }
#pragma unroll
        for (int n = 0; n < 4; ++n) {
            const int ro = (wc * 64 + n * 16 + fr) * 32 + fq * 8;
            bh[n] = *(const f16x8*)(&Bsh[cur][ro]);
            bl[n] = *(const f16x8*)(&Bsl[cur][ro]);
        }
#pragma unroll
        for (int m = 0; m < 2; ++m)
#pragma unroll
            for (int n = 0; n < 4; ++n)
                acc[m][n] = __builtin_amdgcn_mfma_f32_16x16x32_f16(
                    ah[m], bh[n], acc[m][n], 0, 0, 0);
#pragma unroll
        for (int m = 0; m < 2; ++m)
#pragma unroll
            for (int n = 0; n < 4; ++n)
                acc[m][n] = __builtin_amdgcn_mfma_f32_16x16x32_f16(
                    ah[m], bl[n], acc[m][n], 0, 0, 0);
#pragma unroll
        for (int m = 0; m < 2; ++m)
#pragma unroll
            for (int n = 0; n < 4; ++n)
                acc[m][n] = __builtin_amdgcn_mfma_f32_16x16x32_f16(
                    al[m], bh[n], acc[m][n], 0, 0, 0);

        // one barrier per K-step: its auto vmcnt(0) drains the prefetch;
        // the co-resident block computes through our drain window.
        __syncthreads();
        cur ^= 1;
    }

    // C/D layout: col = lane&15, row = (lane>>4)*4 + reg   [m89/m91 verified]
#pragma unroll
    for (int m = 0; m < 2; ++m) {
#pragma unroll
        for (int n = 0; n < 4; ++n) {
#pragma unroll
            for (int r = 0; r < 4; ++r) {
                const int row = m0 + wr * 32 + m * 16 + fq * 4 + r;
                const int col = n0 + wc * 64 + n * 16 + fr;
                float v = acc[m][n][r];
                if (Cadd) v += Cadd[(size_t)row * ldc + col];
                if (radd) v += radd[col];
                if (Cf) Cf[(size_t)row * ldc + col] = v;
                if (Chi) {
                    const f16 hi = (f16)v;
                    Chi[(size_t)row * ldc + col] = hi;
                    Clo[(size_t)row * ldc + col] = (f16)(v - (float)hi);
                }
            }
        }
    }
}

// strided fp32 [rows,cols] (ld) -> contiguous fp16 (hi, lo) pair
__global__ __launch_bounds__(256) void split2d(
    const float* __restrict__ src, int ld, int cols,
    f16* __restrict__ hi, f16* __restrict__ lo, int total4)
{
    const int i = blockIdx.x * 256 + threadIdx.x;
    if (i >= total4) return;
    const int idx = i * 4;
    const int r = idx / cols, c = idx % cols;
    const float4 v = *(const float4*)(src + (size_t)r * ld + c);
    f16x4 h, l;
    h[0] = (f16)v.x; l[0] = (f16)(v.x - (float)h[0]);
    h[1] = (f16)v.y; l[1] = (f16)(v.y - (float)h[1]);
    h[2] = (f16)v.z; l[2] = (f16)(v.z - (float)h[2]);
    h[3] = (f16)v.w; l[3] = (f16)(v.w - (float)h[3]);
    *(f16x4*)(hi + idx) = h;
    *(f16x4*)(lo + idx) = l;
}

// rsum[j] = sum_{k<K} W[j,k]   (the (x+1)-vs-x correction for t==0), fp32
__global__ __launch_bounds__(256) void rowsum_kernel(
    const float* __restrict__ W, int ld, int K, float* __restrict__ out)
{
    const int j = blockIdx.x;
    const int tid = threadIdx.x;
    float s = 0.f;
    for (int k = tid; k < K; k += 256) s += W[(size_t)j * ld + k];
#pragma unroll
    for (int off = 32; off; off >>= 1) s += __shfl_down(s, off);
    __shared__ float red[4];
    if ((tid & 63) == 0) red[tid >> 6] = s;
    __syncthreads();
    if (tid == 0) out[j] = red[0] + red[1] + red[2] + red[3];
}

// Per-step ACT halting + weighted accumulation of hidden. 1 block / row.
// s reconstructed as hi+lo (error ~2^-22 rel) so halting decisions match fp32.
__global__ __launch_bounds__(256) void halt_accum(
    const f16* __restrict__ s_hi, const f16* __restrict__ s_lo,  // [B,H]
    const float* __restrict__ w_halt,  // [H]
    const float* __restrict__ b_halt,  // [1]
    float* __restrict__ hidden,        // [B,H] accumulator (in d_out)
    float* __restrict__ ponder,        // [B]   (in d_out)
    float* __restrict__ cumB,          // [B] state
    float* __restrict__ Rv,            // [B] state
    float* __restrict__ nstep,         // [B] state
    int*   __restrict__ halted,        // [B] state
    int t)
{
    const int b = blockIdx.x;
    const int tid = threadIdx.x;
    const f16x8 vh = *(const f16x8*)(s_hi + (size_t)b * H_SZ + tid * 8);
    const f16x8 vl = *(const f16x8*)(s_lo + (size_t)b * H_SZ + tid * 8);
    float s[8];
#pragma unroll
    for (int j = 0; j < 8; ++j) s[j] = (float)vh[j] + (float)vl[j];
    const float4 w0 = *(const float4*)(w_halt + tid * 8);
    const float4 w1 = *(const float4*)(w_halt + tid * 8 + 4);
    float part = s[0] * w0.x + s[1] * w0.y + s[2] * w0.z + s[3] * w0.w
               + s[4] * w1.x + s[5] * w1.y + s[6] * w1.z + s[7] * w1.w;
#pragma unroll
    for (int off = 32; off; off >>= 1) part += __shfl_down(part, off);

    __shared__ float red[4];
    __shared__ float w_sh;
    if ((tid & 63) == 0) red[tid >> 6] = part;
    __syncthreads();
    if (tid == 0) {
        const float dot = red[0] + red[1] + red[2] + red[3] + b_halt[0];
        const float p = 1.f / (1.f + expf(-dot));
        const float cb = (t == 0) ? 0.f : cumB[b];
        const int   hd = (t == 0) ? 0   : halted[b];
        float w;
        if (hd) {
            w = 0.f;
        } else if (cb + p >= 0.99f || t == TMAX - 1) {
            w = 1.f - cb;                 // remainder R
            halted[b] = 1;
            Rv[b] = w;
            nstep[b] = (float)t;
        } else {
            w = p;
            cumB[b] = cb + p;
            if (t == 0) halted[b] = 0;
        }
        w_sh = w;
        if (t == TMAX - 1) ponder[b] = nstep[b] + 1.f + Rv[b];
    }
    __syncthreads();
    const float w = w_sh;
    if (t > 0 && w == 0.f) return;        // halted rows contribute nothing

    float* hrow = hidden + (size_t)b * H_SZ + tid * 8;
    if (t == 0) {
#pragma unroll
        for (int j = 0; j < 8; ++j) hrow[j] = w * s[j];
    } else {
        float4 h0 = *(const float4*)(hrow);
        float4 h1 = *(const float4*)(hrow + 4);
        h0.x += w * s[0]; h0.y += w * s[1]; h0.z += w * s[2]; h0.w += w * s[3];
        h1.x += w * s[4]; h1.y += w * s[5]; h1.z += w * s[6]; h1.w += w * s[7];
        *(float4*)(hrow)     = h0;
        *(float4*)(hrow + 4) = h1;
    }
}

extern "C" void kernel_launch(void* const* d_in, const int* in_sizes, int n_in,
                              void* d_out, int out_size, void* d_ws, size_t ws_size,
                              hipStream_t stream)
{
    const float* x        = (const float*)d_in[0];   // [B, D_IN]
    const float* h        = (const float*)d_in[1];   // [B, H]
    const float* W_hidden = (const float*)d_in[2];   // [H, D_IN+H]
    const float* b_hidden = (const float*)d_in[3];   // [H]
    const float* w_halt   = (const float*)d_in[4];   // [H]
    const float* b_halt   = (const float*)d_in[5];   // [1]
    const float* W_out    = (const float*)d_in[6];   // [D_OUT, H]
    const float* b_out    = (const float*)d_in[7];   // [D_OUT]

    float* out    = (float*)d_out;
    float* output = out;                                   // [B, D_OUT]
    float* hidden = out + (size_t)B_SZ * D_OUTN;           // [B, H]
    float* ponder = hidden + (size_t)B_SZ * H_SZ;          // [B]

    // ---- workspace layout ----
    float* ws     = (float*)d_ws;
    float* xc     = ws;                                    // [B,H] fp32 16MB
    float* rsum   = xc + (size_t)B_SZ * H_SZ;              // [H]
    float* cumB   = rsum + H_SZ;                           // [B]
    float* Rv     = cumB + B_SZ;                           // [B]
    float* nstep  = Rv + B_SZ;                             // [B]
    int*   halted = (int*)(nstep + B_SZ);                  // [B]
    f16*   fh     = (f16*)(halted + B_SZ);
    f16* xh  = fh;                         // [B,D_IN]  4MB
    f16* xl  = xh  + (size_t)B_SZ * D_INN; // 4MB
    f16* sh0 = xl  + (size_t)B_SZ * D_INN; // [B,H] 8MB
    f16* sl0 = sh0 + (size_t)B_SZ * H_SZ;
    f16* sh1 = sl0 + (size_t)B_SZ * H_SZ;
    f16* sl1 = sh1 + (size_t)B_SZ * H_SZ;
    f16* Wxh = sl1 + (size_t)B_SZ * H_SZ;  // [H,D_IN] 4MB
    f16* Wxl = Wxh + (size_t)H_SZ * D_INN;
    f16* Wsh = Wxl + (size_t)H_SZ * D_INN; // [H,H] 8MB
    f16* Wsl = Wsh + (size_t)H_SZ * H_SZ;
    f16* Woh = Wsl + (size_t)H_SZ * H_SZ;  // [D_OUT,H] 4MB
    f16* Wol = Woh + (size_t)D_OUTN * H_SZ;
    f16* hidh = sh0;                       // reuse after the t-loop
    f16* hidl = sl0;

    const dim3 blk(256);
    const int LDW = D_INN + H_SZ;  // 3072

    // one-time fp32 -> fp16 (hi,lo) splits
    split2d<<<dim3(B_SZ * D_INN / 4 / 256), blk, 0, stream>>>(
        x, D_INN, D_INN, xh, xl, B_SZ * D_INN / 4);
    split2d<<<dim3(B_SZ * H_SZ / 4 / 256), blk, 0, stream>>>(
        h, H_SZ, H_SZ, sh0, sl0, B_SZ * H_SZ / 4);
    split2d<<<dim3(H_SZ * D_INN / 4 / 256), blk, 0, stream>>>(
        W_hidden, LDW, D_INN, Wxh, Wxl, H_SZ * D_INN / 4);
    split2d<<<dim3(H_SZ * H_SZ / 4 / 256), blk, 0, stream>>>(
        W_hidden + D_INN, LDW, H_SZ, Wsh, Wsl, H_SZ * H_SZ / 4);
    split2d<<<dim3(D_OUTN * H_SZ / 4 / 256), blk, 0, stream>>>(
        W_out, H_SZ, H_SZ, Woh, Wol, D_OUTN * H_SZ / 4);

    // rsum[j] = sum_k W_x[j,k]   (xin = x+1 correction at t==0)
    rowsum_kernel<<<dim3(H_SZ), blk, 0, stream>>>(W_hidden, LDW, D_INN, rsum);

    // grid sizes (1-D, XCD-swizzled in-kernel; all % 8 == 0)
    const int g_step = (B_SZ / 64) * (H_SZ / 128);    // 32*16 = 512
    const int g_out  = (B_SZ / 64) * (D_OUTN / 128);  // 32*8  = 256

    // xc = x @ W_x^T + b_hidden   (loop-invariant part, fp32)
    gemm_split<<<dim3(g_step), blk, 0, stream>>>(
        xh, xl, D_INN, Wxh, Wxl, D_INN, nullptr, b_hidden,
        xc, nullptr, nullptr, H_SZ, D_INN, H_SZ / 128);

    for (int t = 0; t < TMAX; ++t) {
        const f16* ph = (t & 1) ? sh1 : sh0;
        const f16* pl = (t & 1) ? sl1 : sl0;
        f16*       nh = (t & 1) ? sh0 : sh1;
        f16*       nl = (t & 1) ? sl0 : sl1;
        // s_new = s_prev @ W_s^T + xc (+ rsum at t==0), written as (hi,lo)
        gemm_split<<<dim3(g_step), blk, 0, stream>>>(
            ph, pl, H_SZ, Wsh, Wsl, H_SZ, xc, (t == 0) ? rsum : nullptr,
            nullptr, nh, nl, H_SZ, H_SZ, H_SZ / 128);
        halt_accum<<<dim3(B_SZ), blk, 0, stream>>>(
            nh, nl, w_halt, b_halt, hidden, ponder, cumB, Rv, nstep, halted, t);
    }

    // output = hidden @ W_out^T + b_out   (Σw = 1 ⇒ projection commutes)
    split2d<<<dim3(B_SZ * H_SZ / 4 / 256), blk, 0, stream>>>(
        hidden, H_SZ, H_SZ, hidh, hidl, B_SZ * H_SZ / 4);
    gemm_split<<<dim3(g_out), blk, 0, stream>>>(
        hidh, hidl, H_SZ, Woh, Wol, H_SZ, nullptr, b_out,
        output, nullptr, nullptr, D_OUTN, H_SZ, D_OUTN / 128);
}

// Round 6
// 1021.159 us; speedup vs baseline: 2.9504x; 1.1136x over previous
//
#include <hip/hip_runtime.h>
#include <hip/hip_bf16.h>
#include <cstdint>

#define B_SZ   2048
#define D_INN  1024
#define H_SZ   2048
#define D_OUTN 1024
#define TMAX   12

typedef _Float16 f16;
typedef __attribute__((ext_vector_type(8))) _Float16 f16x8;
typedef __attribute__((ext_vector_type(4))) _Float16 f16x4;
typedef __attribute__((ext_vector_type(4))) float    f32x4;

typedef const __attribute__((address_space(1))) uint32_t* gptr_t;
typedef __attribute__((address_space(3))) uint32_t*       lptr_t;
__device__ inline void gld16(const void* g, void* l) {   // 16B global->LDS DMA
    __builtin_amdgcn_global_load_lds((gptr_t)g, (lptr_t)l, 16, 0, 0);
}

// ---------------------------------------------------------------------------
// Split-fp16 NT GEMM: C = A·B^T in ~fp32 precision via 3-term Markidis:
//   A = Ahi+Alo, B = Bhi+Blo;  C ≈ Ahi·Bhi + Ahi·Blo + Alo·Bhi   (fp32 accum)
// A [M,K], B [N,K] fp16 row-major.
// Tile 64x128, BK=32, **512 thr / 8 waves** (wave grid 2x4, wave tile 32x32).
// Grid 1-D, nwg=(M/64)*(N/128), XCD-chunked bijective swizzle (nwg%8==0).
// 2 blocks/CU (LDS 48KB/block) x 8 waves = 16 waves/CU = 4 waves/SIMD —
// double the latency-hiding pool of the 256-thr version at identical
// traffic. 2-phase pipeline: STAGE(next) before compute(cur), one barrier.
// Staging map (3 gld16/thread/K-step): waves 0-3 -> Ah, 4-7 -> Al;
// all 8 waves -> Bh; all 8 -> Bl. LDS stays linear row-major [rows][32].
// Epilogue: +Cadd (fp32), +radd; writes Cf (fp32) and/or (Chi, Clo) pair.
// ---------------------------------------------------------------------------
__global__ __launch_bounds__(512, 4) void gemm_split(
    const f16* __restrict__ Ahi, const f16* __restrict__ Alo, int lda,
    const f16* __restrict__ Bhi, const f16* __restrict__ Blo, int ldb,
    const float* __restrict__ Cadd,   // optional [M,ldc] fp32
    const float* __restrict__ radd,   // optional [N] fp32
    float* __restrict__ Cf,           // optional fp32 out
    f16* __restrict__ Chi, f16* __restrict__ Clo,  // optional fp16 pair out
    int ldc, int K, int nx)
{
    __shared__ __align__(16) f16 Ash[2][64 * 32];
    __shared__ __align__(16) f16 Asl[2][64 * 32];
    __shared__ __align__(16) f16 Bsh[2][128 * 32];
    __shared__ __align__(16) f16 Bsl[2][128 * 32];
    const int tid  = threadIdx.x;
    const int wave = tid >> 6;
    const int lane = tid & 63;

    // XCD-chunked bijective blockIdx swizzle (requires nwg % 8 == 0)
    const int nwg = gridDim.x;
    const int cpx = nwg >> 3;
    const int bid = (blockIdx.x & 7) * cpx + (blockIdx.x >> 3);
    const int m0 = (bid / nx) * 64, n0 = (bid % nx) * 128;

    const int wr = wave >> 2, wc = wave & 3;      // wave -> 32x32 sub-tile
    const int fr = lane & 15, fq = lane >> 4;     // fragment row / k-group

    // --- staging maps (16B chunks, LDS linear row-major [rows][32] f16) ---
    // A: 256 chunks; waves 0-3 cover hi, waves 4-7 cover lo
    const int ac   = ((wave & 3) << 6) + lane;     // 0..255
    const int arow = ac >> 2, acol = (ac & 3) * 8;
    const f16* gA = ((wave < 4) ? Ahi : Alo) + (size_t)(m0 + arow) * lda + acol;
    f16* lA = ((wave < 4) ? &Ash[0][0] : &Asl[0][0]) + (ac & ~63) * 8 / 8 * 8;
    // (ac chunk base in f16: chunk index * 8; wave-uniform base = first chunk of wave)
    f16* lAbase = ((wave < 4) ? &Ash[0][0] : &Asl[0][0]) + ((wave & 3) << 9);
    // B: 512 chunks; all 8 waves cover hi then lo
    const int bc   = (wave << 6) + lane;           // 0..511
    const int brow = bc >> 2, bcol = (bc & 3) * 8;
    const f16* gBh = Bhi + (size_t)(n0 + brow) * ldb + bcol;
    const f16* gBl = Blo + (size_t)(n0 + brow) * ldb + bcol;
    const int bofs = wave << 9;                    // f16 offset of wave's 1KB

    f32x4 acc[2][2] = {};

    // prologue: stage tile 0 into buffer 0, full drain once
    gld16(gA,  lAbase);
    gld16(gBh, &Bsh[0][bofs]);
    gld16(gBl, &Bsl[0][bofs]);
    __syncthreads();

    int cur = 0;
    for (int k0 = 0; k0 < K; k0 += 32) {
        // issue next-tile loads first — they fly under this tile's compute
        if (k0 + 32 < K) {
            const int nk = k0 + 32;
            const int nb = cur ^ 1;
            gld16(gA + nk,  lAbase + nb * 2048);
            gld16(gBh + nk, &Bsh[nb][bofs]);
            gld16(gBl + nk, &Bsl[nb][bofs]);
        }

        f16x8 ah[2], al[2], bh[2], bl[2];
#pragma unroll
        for (int m = 0; m < 2; ++m) {
            const int ro = (wr * 32 + m * 16 + fr) * 32 + fq * 8;
            ah[m] = *(const f16x8*)(&Ash[cur][ro]);
            al[m] = *(const f16x8*)(&Asl[cur][ro]);
        }
#pragma unroll
        for (int n = 0; n < 2; ++n) {
            const int ro = (wc * 32 + n * 16 + fr) * 32 + fq * 8;
            bh[n] = *(const f16x8*)(&Bsh[cur][ro]);
            bl[n] = *(const f16x8*)(&Bsl[cur][ro]);
        }
#pragma unroll
        for (int m = 0; m < 2; ++m)
#pragma unroll
            for (int n = 0; n < 2; ++n)
                acc[m][n] = __builtin_amdgcn_mfma_f32_16x16x32_f16(
                    ah[m], bh[n], acc[m][n], 0, 0, 0);
#pragma unroll
        for (int m = 0; m < 2; ++m)
#pragma unroll
            for (int n = 0; n < 2; ++n)
                acc[m][n] = __builtin_amdgcn_mfma_f32_16x16x32_f16(
                    ah[m], bl[n], acc[m][n], 0, 0, 0);
#pragma unroll
        for (int m = 0; m < 2; ++m)
#pragma unroll
            for (int n = 0; n < 2; ++n)
                acc[m][n] = __builtin_amdgcn_mfma_f32_16x16x32_f16(
                    al[m], bh[n], acc[m][n], 0, 0, 0);

        // one barrier per K-step: its auto vmcnt(0) drains the prefetch;
        // 4 waves/SIMD + co-resident block compute through the drain window.
        __syncthreads();
        cur ^= 1;
    }

    // C/D layout: col = lane&15, row = (lane>>4)*4 + reg   [m89/m91 verified]
#pragma unroll
    for (int m = 0; m < 2; ++m) {
#pragma unroll
        for (int n = 0; n < 2; ++n) {
#pragma unroll
            for (int r = 0; r < 4; ++r) {
                const int row = m0 + wr * 32 + m * 16 + fq * 4 + r;
                const int col = n0 + wc * 32 + n * 16 + fr;
                float v = acc[m][n][r];
                if (Cadd) v += Cadd[(size_t)row * ldc + col];
                if (radd) v += radd[col];
                if (Cf) Cf[(size_t)row * ldc + col] = v;
                if (Chi) {
                    const f16 hi = (f16)v;
                    Chi[(size_t)row * ldc + col] = hi;
                    Clo[(size_t)row * ldc + col] = (f16)(v - (float)hi);
                }
            }
        }
    }
}

// strided fp32 [rows,cols] (ld) -> contiguous fp16 (hi, lo) pair
__global__ __launch_bounds__(256) void split2d(
    const float* __restrict__ src, int ld, int cols,
    f16* __restrict__ hi, f16* __restrict__ lo, int total4)
{
    const int i = blockIdx.x * 256 + threadIdx.x;
    if (i >= total4) return;
    const int idx = i * 4;
    const int r = idx / cols, c = idx % cols;
    const float4 v = *(const float4*)(src + (size_t)r * ld + c);
    f16x4 h, l;
    h[0] = (f16)v.x; l[0] = (f16)(v.x - (float)h[0]);
    h[1] = (f16)v.y; l[1] = (f16)(v.y - (float)h[1]);
    h[2] = (f16)v.z; l[2] = (f16)(v.z - (float)h[2]);
    h[3] = (f16)v.w; l[3] = (f16)(v.w - (float)h[3]);
    *(f16x4*)(hi + idx) = h;
    *(f16x4*)(lo + idx) = l;
}

// rsum[j] = sum_{k<K} W[j,k]   (the (x+1)-vs-x correction for t==0), fp32
__global__ __launch_bounds__(256) void rowsum_kernel(
    const float* __restrict__ W, int ld, int K, float* __restrict__ out)
{
    const int j = blockIdx.x;
    const int tid = threadIdx.x;
    float s = 0.f;
    for (int k = tid; k < K; k += 256) s += W[(size_t)j * ld + k];
#pragma unroll
    for (int off = 32; off; off >>= 1) s += __shfl_down(s, off);
    __shared__ float red[4];
    if ((tid & 63) == 0) red[tid >> 6] = s;
    __syncthreads();
    if (tid == 0) out[j] = red[0] + red[1] + red[2] + red[3];
}

// Per-step ACT halting + weighted accumulation of hidden. 1 block / row.
// s reconstructed as hi+lo (error ~2^-22 rel) so halting decisions match fp32.
__global__ __launch_bounds__(256) void halt_accum(
    const f16* __restrict__ s_hi, const f16* __restrict__ s_lo,  // [B,H]
    const float* __restrict__ w_halt,  // [H]
    const float* __restrict__ b_halt,  // [1]
    float* __restrict__ hidden,        // [B,H] accumulator (in d_out)
    float* __restrict__ ponder,        // [B]   (in d_out)
    float* __restrict__ cumB,          // [B] state
    float* __restrict__ Rv,            // [B] state
    float* __restrict__ nstep,         // [B] state
    int*   __restrict__ halted,        // [B] state
    int t)
{
    const int b = blockIdx.x;
    const int tid = threadIdx.x;
    const f16x8 vh = *(const f16x8*)(s_hi + (size_t)b * H_SZ + tid * 8);
    const f16x8 vl = *(const f16x8*)(s_lo + (size_t)b * H_SZ + tid * 8);
    float s[8];
#pragma unroll
    for (int j = 0; j < 8; ++j) s[j] = (float)vh[j] + (float)vl[j];
    const float4 w0 = *(const float4*)(w_halt + tid * 8);
    const float4 w1 = *(const float4*)(w_halt + tid * 8 + 4);
    float part = s[0] * w0.x + s[1] * w0.y + s[2] * w0.z + s[3] * w0.w
               + s[4] * w1.x + s[5] * w1.y + s[6] * w1.z + s[7] * w1.w;
#pragma unroll
    for (int off = 32; off; off >>= 1) part += __shfl_down(part, off);

    __shared__ float red[4];
    __shared__ float w_sh;
    if ((tid & 63) == 0) red[tid >> 6] = part;
    __syncthreads();
    if (tid == 0) {
        const float dot = red[0] + red[1] + red[2] + red[3] + b_halt[0];
        const float p = 1.f / (1.f + expf(-dot));
        const float cb = (t == 0) ? 0.f : cumB[b];
        const int   hd = (t == 0) ? 0   : halted[b];
        float w;
        if (hd) {
            w = 0.f;
        } else if (cb + p >= 0.99f || t == TMAX - 1) {
            w = 1.f - cb;                 // remainder R
            halted[b] = 1;
            Rv[b] = w;
            nstep[b] = (float)t;
        } else {
            w = p;
            cumB[b] = cb + p;
            if (t == 0) halted[b] = 0;
        }
        w_sh = w;
        if (t == TMAX - 1) ponder[b] = nstep[b] + 1.f + Rv[b];
    }
    __syncthreads();
    const float w = w_sh;
    if (t > 0 && w == 0.f) return;        // halted rows contribute nothing

    float* hrow = hidden + (size_t)b * H_SZ + tid * 8;
    if (t == 0) {
#pragma unroll
        for (int j = 0; j < 8; ++j) hrow[j] = w * s[j];
    } else {
        float4 h0 = *(const float4*)(hrow);
        float4 h1 = *(const float4*)(hrow + 4);
        h0.x += w * s[0]; h0.y += w * s[1]; h0.z += w * s[2]; h0.w += w * s[3];
        h1.x += w * s[4]; h1.y += w * s[5]; h1.z += w * s[6]; h1.w += w * s[7];
        *(float4*)(hrow)     = h0;
        *(float4*)(hrow + 4) = h1;
    }
}

extern "C" void kernel_launch(void* const* d_in, const int* in_sizes, int n_in,
                              void* d_out, int out_size, void* d_ws, size_t ws_size,
                              hipStream_t stream)
{
    const float* x        = (const float*)d_in[0];   // [B, D_IN]
    const float* h        = (const float*)d_in[1];   // [B, H]
    const float* W_hidden = (const float*)d_in[2];   // [H, D_IN+H]
    const float* b_hidden = (const float*)d_in[3];   // [H]
    const float* w_halt   = (const float*)d_in[4];   // [H]
    const float* b_halt   = (const float*)d_in[5];   // [1]
    const float* W_out    = (const float*)d_in[6];   // [D_OUT, H]
    const float* b_out    = (const float*)d_in[7];   // [D_OUT]

    float* out    = (float*)d_out;
    float* output = out;                                   // [B, D_OUT]
    float* hidden = out + (size_t)B_SZ * D_OUTN;           // [B, H]
    float* ponder = hidden + (size_t)B_SZ * H_SZ;          // [B]

    // ---- workspace layout ----
    float* ws     = (float*)d_ws;
    float* xc     = ws;                                    // [B,H] fp32 16MB
    float* rsum   = xc + (size_t)B_SZ * H_SZ;              // [H]
    float* cumB   = rsum + H_SZ;                           // [B]
    float* Rv     = cumB + B_SZ;                           // [B]
    float* nstep  = Rv + B_SZ;                             // [B]
    int*   halted = (int*)(nstep + B_SZ);                  // [B]
    f16*   fh     = (f16*)(halted + B_SZ);
    f16* xh  = fh;                         // [B,D_IN]  4MB
    f16* xl  = xh  + (size_t)B_SZ * D_INN; // 4MB
    f16* sh0 = xl  + (size_t)B_SZ * D_INN; // [B,H] 8MB
    f16* sl0 = sh0 + (size_t)B_SZ * H_SZ;
    f16* sh1 = sl0 + (size_t)B_SZ * H_SZ;
    f16* sl1 = sh1 + (size_t)B_SZ * H_SZ;
    f16* Wxh = sl1 + (size_t)B_SZ * H_SZ;  // [H,D_IN] 4MB
    f16* Wxl = Wxh + (size_t)H_SZ * D_INN;
    f16* Wsh = Wxl + (size_t)H_SZ * D_INN; // [H,H] 8MB
    f16* Wsl = Wsh + (size_t)H_SZ * H_SZ;
    f16* Woh = Wsl + (size_t)H_SZ * H_SZ;  // [D_OUT,H] 4MB
    f16* Wol = Woh + (size_t)D_OUTN * H_SZ;
    f16* hidh = sh0;                       // reuse after the t-loop
    f16* hidl = sl0;

    const dim3 blk(256);
    const dim3 gblk(512);
    const int LDW = D_INN + H_SZ;  // 3072

    // one-time fp32 -> fp16 (hi,lo) splits
    split2d<<<dim3(B_SZ * D_INN / 4 / 256), blk, 0, stream>>>(
        x, D_INN, D_INN, xh, xl, B_SZ * D_INN / 4);
    split2d<<<dim3(B_SZ * H_SZ / 4 / 256), blk, 0, stream>>>(
        h, H_SZ, H_SZ, sh0, sl0, B_SZ * H_SZ / 4);
    split2d<<<dim3(H_SZ * D_INN / 4 / 256), blk, 0, stream>>>(
        W_hidden, LDW, D_INN, Wxh, Wxl, H_SZ * D_INN / 4);
    split2d<<<dim3(H_SZ * H_SZ / 4 / 256), blk, 0, stream>>>(
        W_hidden + D_INN, LDW, H_SZ, Wsh, Wsl, H_SZ * H_SZ / 4);
    split2d<<<dim3(D_OUTN * H_SZ / 4 / 256), blk, 0, stream>>>(
        W_out, H_SZ, H_SZ, Woh, Wol, D_OUTN * H_SZ / 4);

    // rsum[j] = sum_k W_x[j,k]   (xin = x+1 correction at t==0)
    rowsum_kernel<<<dim3(H_SZ), blk, 0, stream>>>(W_hidden, LDW, D_INN, rsum);

    // grid sizes (1-D, XCD-swizzled in-kernel; all % 8 == 0)
    const int g_step = (B_SZ / 64) * (H_SZ / 128);    // 32*16 = 512
    const int g_out  = (B_SZ / 64) * (D_OUTN / 128);  // 32*8  = 256

    // xc = x @ W_x^T + b_hidden   (loop-invariant part, fp32)
    gemm_split<<<dim3(g_step), gblk, 0, stream>>>(
        xh, xl, D_INN, Wxh, Wxl, D_INN, nullptr, b_hidden,
        xc, nullptr, nullptr, H_SZ, D_INN, H_SZ / 128);

    for (int t = 0; t < TMAX; ++t) {
        const f16* ph = (t & 1) ? sh1 : sh0;
        const f16* pl = (t & 1) ? sl1 : sl0;
        f16*       nh = (t & 1) ? sh0 : sh1;
        f16*       nl = (t & 1) ? sl0 : sl1;
        // s_new = s_prev @ W_s^T + xc (+ rsum at t==0), written as (hi,lo)
        gemm_split<<<dim3(g_step), gblk, 0, stream>>>(
            ph, pl, H_SZ, Wsh, Wsl, H_SZ, xc, (t == 0) ? rsum : nullptr,
            nullptr, nh, nl, H_SZ, H_SZ, H_SZ / 128);
        halt_accum<<<dim3(B_SZ), blk, 0, stream>>>(
            nh, nl, w_halt, b_halt, hidden, ponder, cumB, Rv, nstep, halted, t);
    }

    // output = hidden @ W_out^T + b_out   (Σw = 1 ⇒ projection commutes)
    split2d<<<dim3(B_SZ * H_SZ / 4 / 256), blk, 0, stream>>>(
        hidden, H_SZ, H_SZ, hidh, hidl, B_SZ * H_SZ / 4);
    gemm_split<<<dim3(g_out), gblk, 0, stream>>>(
        hidh, hidl, H_SZ, Woh, Wol, H_SZ, nullptr, b_out,
        output, nullptr, nullptr, D_OUTN, H_SZ, D_OUTN / 128);
}

// Round 7
// 992.102 us; speedup vs baseline: 3.0368x; 1.0293x over previous
//
#include <hip/hip_runtime.h>
#include <hip/hip_bf16.h>
#include <cstdint>

#define B_SZ   2048
#define D_INN  1024
#define H_SZ   2048
#define D_OUTN 1024
#define TMAX   12

typedef _Float16 f16;
typedef __attribute__((ext_vector_type(8))) _Float16 f16x8;
typedef __attribute__((ext_vector_type(4))) _Float16 f16x4;
typedef __attribute__((ext_vector_type(4))) float    f32x4;

typedef const __attribute__((address_space(1))) uint32_t* gptr_t;
typedef __attribute__((address_space(3))) uint32_t*       lptr_t;
__device__ inline void gld16(const void* g, void* l) {   // 16B global->LDS DMA
    __builtin_amdgcn_global_load_lds((gptr_t)g, (lptr_t)l, 16, 0, 0);
}

// ---------------------------------------------------------------------------
// Split-fp16 NT GEMM: C = A·B^T in ~fp32 precision via 3-term Markidis:
//   A = Ahi+Alo, B = Bhi+Blo;  C ≈ Ahi·Bhi + Ahi·Blo + Alo·Bhi   (fp32 accum)
// A [M,K], B [N,K] fp16 row-major.
// Tile 64x128, BK=32, 512 thr / 8 waves (wave grid 2x4, wave tile 32x32).
// Grid 1-D, XCD-chunked bijective swizzle (nwg%8==0). 2 blocks/CU.
//
// This round:
//  * T4-lite pipeline: 3 LDS buffers, prefetch distance 1, raw s_barrier +
//    counted s_waitcnt vmcnt(3) (never 0 in-loop) — loads stay in flight
//    across the barrier instead of the __syncthreads vmcnt(0) drain.
//    Race-safe: written buffer is 2 barriers from any reader (3-buf slack).
//  * T2 LDS swizzle (both-sides): read byte ^= ((row>>1)&3)<<4 kills the
//    8-way bank conflict of row-stride-64B b128 reads; global source chunk
//    pre-permuted with the same involution (c ^= (c>>3)&3) so the linear
//    global_load_lds dest matches (rule #21).
// Epilogue: +Cadd (fp32), +radd; writes Cf (fp32) and/or (Chi, Clo) pair.
// ---------------------------------------------------------------------------
__global__ __launch_bounds__(512, 4) void gemm_split(
    const f16* __restrict__ Ahi, const f16* __restrict__ Alo, int lda,
    const f16* __restrict__ Bhi, const f16* __restrict__ Blo, int ldb,
    const float* __restrict__ Cadd,   // optional [M,ldc] fp32
    const float* __restrict__ radd,   // optional [N] fp32
    float* __restrict__ Cf,           // optional fp32 out
    f16* __restrict__ Chi, f16* __restrict__ Clo,  // optional fp16 pair out
    int ldc, int K, int nx)
{
    __shared__ __align__(16) f16 Ash[3][64 * 32];
    __shared__ __align__(16) f16 Asl[3][64 * 32];
    __shared__ __align__(16) f16 Bsh[3][128 * 32];
    __shared__ __align__(16) f16 Bsl[3][128 * 32];
    const int tid  = threadIdx.x;
    const int wave = tid >> 6;
    const int lane = tid & 63;

    // XCD-chunked bijective blockIdx swizzle (requires nwg % 8 == 0)
    const int nwg = gridDim.x;
    const int cpx = nwg >> 3;
    const int bid = (blockIdx.x & 7) * cpx + (blockIdx.x >> 3);
    const int m0 = (bid / nx) * 64, n0 = (bid % nx) * 128;

    const int wr = wave >> 2, wc = wave & 3;      // wave -> 32x32 sub-tile
    const int fr = lane & 15, fq = lane >> 4;     // fragment row / k-group

    // --- staging maps: LDS dest linear 16B chunks, global source chunk
    //     pre-permuted by the involution c ^= (c>>3)&3 (== byte^((row>>1)&3)<<4)
    // A: 256 chunks; waves 0-3 cover hi, waves 4-7 cover lo
    const int ac   = ((wave & 3) << 6) + lane;     // 0..255 (this thread's chunk)
    const int acs  = ac ^ ((ac >> 3) & 3);         // swizzled source chunk
    const int arow = acs >> 2, acol = (acs & 3) * 8;
    const f16* gA = ((wave < 4) ? Ahi : Alo) + (size_t)(m0 + arow) * lda + acol;
    f16* dstA0 = (wave < 4) ? &Ash[0][0] : &Asl[0][0];
    const int aofs = (wave & 3) << 9;              // wave-uniform dest base (f16)
    // B: 512 chunks; all 8 waves cover hi and lo
    const int bc   = (wave << 6) + lane;           // 0..511
    const int bcs  = bc ^ ((bc >> 3) & 3);
    const int brow = bcs >> 2, bcol = (bcs & 3) * 8;
    const f16* gBh = Bhi + (size_t)(n0 + brow) * ldb + bcol;
    const f16* gBl = Blo + (size_t)(n0 + brow) * ldb + bcol;
    const int bofs = wave << 9;

    // precomputed swizzled read offsets (f16 units), k-invariant
    int offA[2], offB[2];
#pragma unroll
    for (int m = 0; m < 2; ++m) {
        const int row = wr * 32 + m * 16 + fr;
        offA[m] = row * 32 + ((fq ^ ((row >> 1) & 3)) << 3);
    }
#pragma unroll
    for (int n = 0; n < 2; ++n) {
        const int row = wc * 32 + n * 16 + fr;
        offB[n] = row * 32 + ((fq ^ ((row >> 1) & 3)) << 3);
    }

    f32x4 acc[2][2] = {};

    // prologue: stage tile 0 into buffer 0 (3 loads/thread)
    gld16(gA,  dstA0 + aofs);
    gld16(gBh, &Bsh[0][bofs]);
    gld16(gBl, &Bsl[0][bofs]);

    const int nk = K >> 5;
    int cur = 0;
    for (int ki = 0; ki < nk; ++ki) {
        const int nxt = (cur == 2) ? 0 : cur + 1;
        if (ki + 1 < nk) {
            const int ko = (ki + 1) << 5;
            gld16(gA + ko,  dstA0 + nxt * 2048 + aofs);
            gld16(gBh + ko, &Bsh[nxt][bofs]);
            gld16(gBl + ko, &Bsl[nxt][bofs]);
            // wait for tile ki only; keep tile ki+1's 3 loads in flight
            asm volatile("s_waitcnt vmcnt(3)" ::: "memory");
        } else {
            asm volatile("s_waitcnt vmcnt(0)" ::: "memory");
        }
        __builtin_amdgcn_s_barrier();
        asm volatile("" ::: "memory");   // keep ds_reads below the barrier

        f16x8 ah[2], al[2], bh[2], bl[2];
#pragma unroll
        for (int m = 0; m < 2; ++m) {
            ah[m] = *(const f16x8*)(&Ash[cur][offA[m]]);
            al[m] = *(const f16x8*)(&Asl[cur][offA[m]]);
        }
#pragma unroll
        for (int n = 0; n < 2; ++n) {
            bh[n] = *(const f16x8*)(&Bsh[cur][offB[n]]);
            bl[n] = *(const f16x8*)(&Bsl[cur][offB[n]]);
        }
#pragma unroll
        for (int m = 0; m < 2; ++m)
#pragma unroll
            for (int n = 0; n < 2; ++n)
                acc[m][n] = __builtin_amdgcn_mfma_f32_16x16x32_f16(
                    ah[m], bh[n], acc[m][n], 0, 0, 0);
#pragma unroll
        for (int m = 0; m < 2; ++m)
#pragma unroll
            for (int n = 0; n < 2; ++n)
                acc[m][n] = __builtin_amdgcn_mfma_f32_16x16x32_f16(
                    ah[m], bl[n], acc[m][n], 0, 0, 0);
#pragma unroll
        for (int m = 0; m < 2; ++m)
#pragma unroll
            for (int n = 0; n < 2; ++n)
                acc[m][n] = __builtin_amdgcn_mfma_f32_16x16x32_f16(
                    al[m], bh[n], acc[m][n], 0, 0, 0);
        cur = nxt;
    }

    // C/D layout: col = lane&15, row = (lane>>4)*4 + reg   [m89/m91 verified]
#pragma unroll
    for (int m = 0; m < 2; ++m) {
#pragma unroll
        for (int n = 0; n < 2; ++n) {
#pragma unroll
            for (int r = 0; r < 4; ++r) {
                const int row = m0 + wr * 32 + m * 16 + fq * 4 + r;
                const int col = n0 + wc * 32 + n * 16 + fr;
                float v = acc[m][n][r];
                if (Cadd) v += Cadd[(size_t)row * ldc + col];
                if (radd) v += radd[col];
                if (Cf) Cf[(size_t)row * ldc + col] = v;
                if (Chi) {
                    const f16 hi = (f16)v;
                    Chi[(size_t)row * ldc + col] = hi;
                    Clo[(size_t)row * ldc + col] = (f16)(v - (float)hi);
                }
            }
        }
    }
}

// strided fp32 [rows,cols] (ld) -> contiguous fp16 (hi, lo) pair
__global__ __launch_bounds__(256) void split2d(
    const float* __restrict__ src, int ld, int cols,
    f16* __restrict__ hi, f16* __restrict__ lo, int total4)
{
    const int i = blockIdx.x * 256 + threadIdx.x;
    if (i >= total4) return;
    const int idx = i * 4;
    const int r = idx / cols, c = idx % cols;
    const float4 v = *(const float4*)(src + (size_t)r * ld + c);
    f16x4 h, l;
    h[0] = (f16)v.x; l[0] = (f16)(v.x - (float)h[0]);
    h[1] = (f16)v.y; l[1] = (f16)(v.y - (float)h[1]);
    h[2] = (f16)v.z; l[2] = (f16)(v.z - (float)h[2]);
    h[3] = (f16)v.w; l[3] = (f16)(v.w - (float)h[3]);
    *(f16x4*)(hi + idx) = h;
    *(f16x4*)(lo + idx) = l;
}

// rsum[j] = sum_{k<K} W[j,k]   (the (x+1)-vs-x correction for t==0), fp32
__global__ __launch_bounds__(256) void rowsum_kernel(
    const float* __restrict__ W, int ld, int K, float* __restrict__ out)
{
    const int j = blockIdx.x;
    const int tid = threadIdx.x;
    float s = 0.f;
    for (int k = tid; k < K; k += 256) s += W[(size_t)j * ld + k];
#pragma unroll
    for (int off = 32; off; off >>= 1) s += __shfl_down(s, off);
    __shared__ float red[4];
    if ((tid & 63) == 0) red[tid >> 6] = s;
    __syncthreads();
    if (tid == 0) out[j] = red[0] + red[1] + red[2] + red[3];
}

// Per-step ACT halting + weighted accumulation of hidden. 1 block / row.
// s reconstructed as hi+lo (error ~2^-22 rel) so halting decisions match fp32.
__global__ __launch_bounds__(256) void halt_accum(
    const f16* __restrict__ s_hi, const f16* __restrict__ s_lo,  // [B,H]
    const float* __restrict__ w_halt,  // [H]
    const float* __restrict__ b_halt,  // [1]
    float* __restrict__ hidden,        // [B,H] accumulator (in d_out)
    float* __restrict__ ponder,        // [B]   (in d_out)
    float* __restrict__ cumB,          // [B] state
    float* __restrict__ Rv,            // [B] state
    float* __restrict__ nstep,         // [B] state
    int*   __restrict__ halted,        // [B] state
    int t)
{
    const int b = blockIdx.x;
    const int tid = threadIdx.x;
    const f16x8 vh = *(const f16x8*)(s_hi + (size_t)b * H_SZ + tid * 8);
    const f16x8 vl = *(const f16x8*)(s_lo + (size_t)b * H_SZ + tid * 8);
    float s[8];
#pragma unroll
    for (int j = 0; j < 8; ++j) s[j] = (float)vh[j] + (float)vl[j];
    const float4 w0 = *(const float4*)(w_halt + tid * 8);
    const float4 w1 = *(const float4*)(w_halt + tid * 8 + 4);
    float part = s[0] * w0.x + s[1] * w0.y + s[2] * w0.z + s[3] * w0.w
               + s[4] * w1.x + s[5] * w1.y + s[6] * w1.z + s[7] * w1.w;
#pragma unroll
    for (int off = 32; off; off >>= 1) part += __shfl_down(part, off);

    __shared__ float red[4];
    __shared__ float w_sh;
    if ((tid & 63) == 0) red[tid >> 6] = part;
    __syncthreads();
    if (tid == 0) {
        const float dot = red[0] + red[1] + red[2] + red[3] + b_halt[0];
        const float p = 1.f / (1.f + expf(-dot));
        const float cb = (t == 0) ? 0.f : cumB[b];
        const int   hd = (t == 0) ? 0   : halted[b];
        float w;
        if (hd) {
            w = 0.f;
        } else if (cb + p >= 0.99f || t == TMAX - 1) {
            w = 1.f - cb;                 // remainder R
            halted[b] = 1;
            Rv[b] = w;
            nstep[b] = (float)t;
        } else {
            w = p;
            cumB[b] = cb + p;
            if (t == 0) halted[b] = 0;
        }
        w_sh = w;
        if (t == TMAX - 1) ponder[b] = nstep[b] + 1.f + Rv[b];
    }
    __syncthreads();
    const float w = w_sh;
    if (t > 0 && w == 0.f) return;        // halted rows contribute nothing

    float* hrow = hidden + (size_t)b * H_SZ + tid * 8;
    if (t == 0) {
#pragma unroll
        for (int j = 0; j < 8; ++j) hrow[j] = w * s[j];
    } else {
        float4 h0 = *(const float4*)(hrow);
        float4 h1 = *(const float4*)(hrow + 4);
        h0.x += w * s[0]; h0.y += w * s[1]; h0.z += w * s[2]; h0.w += w * s[3];
        h1.x += w * s[4]; h1.y += w * s[5]; h1.z += w * s[6]; h1.w += w * s[7];
        *(float4*)(hrow)     = h0;
        *(float4*)(hrow + 4) = h1;
    }
}

extern "C" void kernel_launch(void* const* d_in, const int* in_sizes, int n_in,
                              void* d_out, int out_size, void* d_ws, size_t ws_size,
                              hipStream_t stream)
{
    const float* x        = (const float*)d_in[0];   // [B, D_IN]
    const float* h        = (const float*)d_in[1];   // [B, H]
    const float* W_hidden = (const float*)d_in[2];   // [H, D_IN+H]
    const float* b_hidden = (const float*)d_in[3];   // [H]
    const float* w_halt   = (const float*)d_in[4];   // [H]
    const float* b_halt   = (const float*)d_in[5];   // [1]
    const float* W_out    = (const float*)d_in[6];   // [D_OUT, H]
    const float* b_out    = (const float*)d_in[7];   // [D_OUT]

    float* out    = (float*)d_out;
    float* output = out;                                   // [B, D_OUT]
    float* hidden = out + (size_t)B_SZ * D_OUTN;           // [B, H]
    float* ponder = hidden + (size_t)B_SZ * H_SZ;          // [B]

    // ---- workspace layout ----
    float* ws     = (float*)d_ws;
    float* xc     = ws;                                    // [B,H] fp32 16MB
    float* rsum   = xc + (size_t)B_SZ * H_SZ;              // [H]
    float* cumB   = rsum + H_SZ;                           // [B]
    float* Rv     = cumB + B_SZ;                           // [B]
    float* nstep  = Rv + B_SZ;                             // [B]
    int*   halted = (int*)(nstep + B_SZ);                  // [B]
    f16*   fh     = (f16*)(halted + B_SZ);
    f16* xh  = fh;                         // [B,D_IN]  4MB
    f16* xl  = xh  + (size_t)B_SZ * D_INN; // 4MB
    f16* sh0 = xl  + (size_t)B_SZ * D_INN; // [B,H] 8MB
    f16* sl0 = sh0 + (size_t)B_SZ * H_SZ;
    f16* sh1 = sl0 + (size_t)B_SZ * H_SZ;
    f16* sl1 = sh1 + (size_t)B_SZ * H_SZ;
    f16* Wxh = sl1 + (size_t)B_SZ * H_SZ;  // [H,D_IN] 4MB
    f16* Wxl = Wxh + (size_t)H_SZ * D_INN;
    f16* Wsh = Wxl + (size_t)H_SZ * D_INN; // [H,H] 8MB
    f16* Wsl = Wsh + (size_t)H_SZ * H_SZ;
    f16* Woh = Wsl + (size_t)H_SZ * H_SZ;  // [D_OUT,H] 4MB
    f16* Wol = Woh + (size_t)D_OUTN * H_SZ;
    f16* hidh = sh0;                       // reuse after the t-loop
    f16* hidl = sl0;

    const dim3 blk(256);
    const dim3 gblk(512);
    const int LDW = D_INN + H_SZ;  // 3072

    // one-time fp32 -> fp16 (hi,lo) splits
    split2d<<<dim3(B_SZ * D_INN / 4 / 256), blk, 0, stream>>>(
        x, D_INN, D_INN, xh, xl, B_SZ * D_INN / 4);
    split2d<<<dim3(B_SZ * H_SZ / 4 / 256), blk, 0, stream>>>(
        h, H_SZ, H_SZ, sh0, sl0, B_SZ * H_SZ / 4);
    split2d<<<dim3(H_SZ * D_INN / 4 / 256), blk, 0, stream>>>(
        W_hidden, LDW, D_INN, Wxh, Wxl, H_SZ * D_INN / 4);
    split2d<<<dim3(H_SZ * H_SZ / 4 / 256), blk, 0, stream>>>(
        W_hidden + D_INN, LDW, H_SZ, Wsh, Wsl, H_SZ * H_SZ / 4);
    split2d<<<dim3(D_OUTN * H_SZ / 4 / 256), blk, 0, stream>>>(
        W_out, H_SZ, H_SZ, Woh, Wol, D_OUTN * H_SZ / 4);

    // rsum[j] = sum_k W_x[j,k]   (xin = x+1 correction at t==0)
    rowsum_kernel<<<dim3(H_SZ), blk, 0, stream>>>(W_hidden, LDW, D_INN, rsum);

    // grid sizes (1-D, XCD-swizzled in-kernel; all % 8 == 0)
    const int g_step = (B_SZ / 64) * (H_SZ / 128);    // 32*16 = 512
    const int g_out  = (B_SZ / 64) * (D_OUTN / 128);  // 32*8  = 256

    // xc = x @ W_x^T + b_hidden   (loop-invariant part, fp32)
    gemm_split<<<dim3(g_step), gblk, 0, stream>>>(
        xh, xl, D_INN, Wxh, Wxl, D_INN, nullptr, b_hidden,
        xc, nullptr, nullptr, H_SZ, D_INN, H_SZ / 128);

    for (int t = 0; t < TMAX; ++t) {
        const f16* ph = (t & 1) ? sh1 : sh0;
        const f16* pl = (t & 1) ? sl1 : sl0;
        f16*       nh = (t & 1) ? sh0 : sh1;
        f16*       nl = (t & 1) ? sl0 : sl1;
        // s_new = s_prev @ W_s^T + xc (+ rsum at t==0), written as (hi,lo)
        gemm_split<<<dim3(g_step), gblk, 0, stream>>>(
            ph, pl, H_SZ, Wsh, Wsl, H_SZ, xc, (t == 0) ? rsum : nullptr,
            nullptr, nh, nl, H_SZ, H_SZ, H_SZ / 128);
        halt_accum<<<dim3(B_SZ), blk, 0, stream>>>(
            nh, nl, w_halt, b_halt, hidden, ponder, cumB, Rv, nstep, halted, t);
    }

    // output = hidden @ W_out^T + b_out   (Σw = 1 ⇒ projection commutes)
    split2d<<<dim3(B_SZ * H_SZ / 4 / 256), blk, 0, stream>>>(
        hidden, H_SZ, H_SZ, hidh, hidl, B_SZ * H_SZ / 4);
    gemm_split<<<dim3(g_out), gblk, 0, stream>>>(
        hidh, hidl, H_SZ, Woh, Wol, H_SZ, nullptr, b_out,
        output, nullptr, nullptr, D_OUTN, H_SZ, D_OUTN / 128);
}